// Round 1
// baseline (3535.752 us; speedup 1.0000x reference)
//
#include <hip/hip_runtime.h>
#include <math.h>

#define NEG_SLOPE 0.2f

static const int NN = 100000;   // nodes per branch
static const int EE = 1600000;  // edges per branch
static const int BB = 512;      // graphs
static const int DD = 256;      // input dim

__device__ __forceinline__ float leaky(float x) { return x >= 0.f ? x : NEG_SLOPE * x; }

// monotone float<->uint mapping for atomicMax on signed floats
__device__ __forceinline__ unsigned ford(float f) {
    unsigned b = __float_as_uint(f);
    return (b & 0x80000000u) ? ~b : (b | 0x80000000u);
}
__device__ __forceinline__ float funord(unsigned u) {
    return (u & 0x80000000u) ? __uint_as_float(u & 0x7fffffffu) : __uint_as_float(~u);
}

// ---------------- GEMM: C[M,N] = A[M,K] @ B[K,N], f32, BM=BN=64, BK=16 ----------------
__global__ void gemm64_kernel(const float* __restrict__ A, const float* __restrict__ B,
                              float* __restrict__ C, int M, int N, int K) {
    __shared__ float As[16][65];
    __shared__ float Bs[16][64];
    const int tid = threadIdx.x;
    const int tx = tid & 15, ty = tid >> 4;
    const int row0 = blockIdx.y * 64, col0 = blockIdx.x * 64;
    float acc[4][4] = {};
    for (int k0 = 0; k0 < K; k0 += 16) {
        #pragma unroll
        for (int i = 0; i < 4; i++) {
            int li = tid + i * 256;         // 0..1023
            int m = li >> 4, k = li & 15;
            int r = row0 + m;
            As[k][m] = (r < M) ? A[(size_t)r * K + k0 + k] : 0.f;
        }
        #pragma unroll
        for (int i = 0; i < 4; i++) {
            int li = tid + i * 256;
            int kk = li >> 6, n = li & 63;
            Bs[kk][n] = B[(size_t)(k0 + kk) * N + col0 + n];
        }
        __syncthreads();
        #pragma unroll
        for (int k = 0; k < 16; k++) {
            float am[4], bn[4];
            #pragma unroll
            for (int i = 0; i < 4; i++) am[i] = As[k][ty * 4 + i];
            #pragma unroll
            for (int j = 0; j < 4; j++) bn[j] = Bs[k][tx * 4 + j];
            #pragma unroll
            for (int i = 0; i < 4; i++)
                #pragma unroll
                for (int j = 0; j < 4; j++) acc[i][j] += am[i] * bn[j];
        }
        __syncthreads();
    }
    #pragma unroll
    for (int i = 0; i < 4; i++) {
        int r = row0 + ty * 4 + i;
        if (r >= M) continue;
        #pragma unroll
        for (int j = 0; j < 4; j++) C[(size_t)r * N + col0 + tx * 4 + j] = acc[i][j];
    }
}

// ---------------- per-node: al_s/al_d dots + self-loop e + seed max ----------------
template <int DOUT>
__global__ void node_al_kernel(const float* __restrict__ h,
                               const float* __restrict__ a_src, const float* __restrict__ a_dst,
                               float* __restrict__ al_s, float* __restrict__ al_d,
                               float* __restrict__ es, unsigned* __restrict__ m_ord, int n) {
    int node = (blockIdx.x * blockDim.x + threadIdx.x) >> 6;
    int lane = threadIdx.x & 63;
    if (node >= n) return;
    const float* hp = h + (size_t)node * DOUT;
    float sa = 0.f, da = 0.f;
    #pragma unroll
    for (int c = lane; c < DOUT; c += 64) {
        float hv = hp[c];
        sa += hv * a_src[c];
        da += hv * a_dst[c];
    }
    #pragma unroll
    for (int off = 32; off > 0; off >>= 1) {
        sa += __shfl_down(sa, off);
        da += __shfl_down(da, off);
    }
    if (lane == 0) {
        al_s[node] = sa;
        al_d[node] = da;
        float e = leaky(sa + da);
        es[node] = e;
        m_ord[node] = ford(e);   // self-loop seeds the segment max
    }
}

// ---------------- per-edge: segment max via ordered atomicMax ----------------
__global__ void edge_max_kernel(const int* __restrict__ src, const int* __restrict__ dst,
                                const float* __restrict__ al_s, const float* __restrict__ al_d,
                                unsigned* __restrict__ m_ord, int ne) {
    int e = blockIdx.x * blockDim.x + threadIdx.x;
    if (e >= ne) return;
    int s = src[e], d = dst[e];
    float ev = leaky(al_s[s] + al_d[d]);
    atomicMax(&m_ord[d], ford(ev));
}

// ---------------- per-node: decode max, init denom with self-loop term ----------------
__global__ void node_finish_kernel(const unsigned* __restrict__ m_ord, const float* __restrict__ es,
                                   float* __restrict__ m_f, float* __restrict__ denom, int n) {
    int i = blockIdx.x * blockDim.x + threadIdx.x;
    if (i >= n) return;
    float m = funord(m_ord[i]);
    m_f[i] = m;
    denom[i] = expf(es[i] - m);
}

// ---------------- per-edge: denom accumulation ----------------
__global__ void edge_denom_kernel(const int* __restrict__ src, const int* __restrict__ dst,
                                  const float* __restrict__ al_s, const float* __restrict__ al_d,
                                  const float* __restrict__ m_f, float* __restrict__ denom, int ne) {
    int e = blockIdx.x * blockDim.x + threadIdx.x;
    if (e >= ne) return;
    int s = src[e], d = dst[e];
    float ev = leaky(al_s[s] + al_d[d]);
    atomicAdd(&denom[d], expf(ev - m_f[d]));
}

// ---------------- per-node: out = b + h*alpha_self ----------------
template <int DOUT>
__global__ void node_self_out_kernel(const float* __restrict__ h, const float* __restrict__ bias,
                                     const float* __restrict__ es, const float* __restrict__ m_f,
                                     const float* __restrict__ denom, float* __restrict__ out, int n) {
    int node = (blockIdx.x * blockDim.x + threadIdx.x) >> 6;
    int lane = threadIdx.x & 63;
    if (node >= n) return;
    float alpha = expf(es[node] - m_f[node]) / denom[node];
    const float* hp = h + (size_t)node * DOUT;
    float* op = out + (size_t)node * DOUT;
    #pragma unroll
    for (int c = lane; c < DOUT; c += 64) op[c] = bias[c] + hp[c] * alpha;
}

// ---------------- per-edge: out[dst] += h[src]*alpha (one wave per edge) ----------------
template <int DOUT>
__global__ void edge_scatter_kernel(const int* __restrict__ src, const int* __restrict__ dst,
                                    const float* __restrict__ al_s, const float* __restrict__ al_d,
                                    const float* __restrict__ m_f, const float* __restrict__ denom,
                                    const float* __restrict__ h, float* __restrict__ out, int ne) {
    int e = (blockIdx.x * blockDim.x + threadIdx.x) >> 6;
    int lane = threadIdx.x & 63;
    if (e >= ne) return;
    int s = src[e], d = dst[e];
    float ev = leaky(al_s[s] + al_d[d]);
    float alpha = expf(ev - m_f[d]) / denom[d];
    const float* hp = h + (size_t)s * DOUT;
    float* op = out + (size_t)d * DOUT;
    #pragma unroll
    for (int c = lane; c < DOUT; c += 64) atomicAdd(&op[c], hp[c] * alpha);
}

// ---------------- mean-pool accumulation (one wave per node, DOUT=64) ----------------
__global__ void pool_kernel(const float* __restrict__ x, const int* __restrict__ batch,
                            float* __restrict__ pooled, float* __restrict__ cnt, int n) {
    int node = (blockIdx.x * blockDim.x + threadIdx.x) >> 6;
    int lane = threadIdx.x & 63;
    if (node >= n) return;
    int b = batch[node];
    atomicAdd(&pooled[(size_t)b * 64 + lane], x[(size_t)node * 64 + lane]);
    if (lane == 0) atomicAdd(&cnt[b], 1.f);
}

// ---------------- final: sigmoid((xs+xt)@lin_w + lin_b) ----------------
__global__ void final_kernel(const float* __restrict__ ps, const float* __restrict__ pt,
                             const float* __restrict__ cs, const float* __restrict__ ct,
                             const float* __restrict__ lw, const float* __restrict__ lb,
                             float* __restrict__ out) {
    int g = blockIdx.x;
    int c = threadIdx.x;
    if (c >= 27) return;
    float ics = 1.f / fmaxf(cs[g], 1.f);
    float ict = 1.f / fmaxf(ct[g], 1.f);
    float acc = lb[c];
    #pragma unroll 8
    for (int k = 0; k < 64; k++) {
        float xv = ps[g * 64 + k] * ics + pt[g * 64 + k] * ict;
        acc += xv * lw[k * 27 + c];
    }
    out[g * 27 + c] = 1.f / (1.f + expf(-acc));
}

// ---------------- one GAT conv layer ----------------
static void run_conv(const float* x, int din, int dout,
                     const float* W, const float* a_src, const float* a_dst, const float* bias,
                     const int* src, const int* dst,
                     float* h, float* out,
                     float* al_s, float* al_d, float* es, float* m_f, float* denom, unsigned* m_ord,
                     hipStream_t stream) {
    dim3 ggrid(dout / 64, (NN + 63) / 64);
    gemm64_kernel<<<ggrid, 256, 0, stream>>>(x, W, h, NN, dout, din);

    int node_wave_blocks = (NN * 64 + 255) / 256;
    int edge_blocks = (EE + 255) / 256;
    int edge_wave_blocks = (EE * 64 + 255) / 256;

    if (dout == 128) {
        node_al_kernel<128><<<node_wave_blocks, 256, 0, stream>>>(h, a_src, a_dst, al_s, al_d, es, m_ord, NN);
    } else {
        node_al_kernel<64><<<node_wave_blocks, 256, 0, stream>>>(h, a_src, a_dst, al_s, al_d, es, m_ord, NN);
    }
    edge_max_kernel<<<edge_blocks, 256, 0, stream>>>(src, dst, al_s, al_d, m_ord, EE);
    node_finish_kernel<<<(NN + 255) / 256, 256, 0, stream>>>(m_ord, es, m_f, denom, NN);
    edge_denom_kernel<<<edge_blocks, 256, 0, stream>>>(src, dst, al_s, al_d, m_f, denom, EE);
    if (dout == 128) {
        node_self_out_kernel<128><<<node_wave_blocks, 256, 0, stream>>>(h, bias, es, m_f, denom, out, NN);
        edge_scatter_kernel<128><<<edge_wave_blocks, 256, 0, stream>>>(src, dst, al_s, al_d, m_f, denom, h, out, EE);
    } else {
        node_self_out_kernel<64><<<node_wave_blocks, 256, 0, stream>>>(h, bias, es, m_f, denom, out, NN);
        edge_scatter_kernel<64><<<edge_wave_blocks, 256, 0, stream>>>(src, dst, al_s, al_d, m_f, denom, h, out, EE);
    }
}

extern "C" void kernel_launch(void* const* d_in, const int* in_sizes, int n_in,
                              void* d_out, int out_size, void* d_ws, size_t ws_size,
                              hipStream_t stream) {
    const float* x_s = (const float*)d_in[0];
    const float* x_t = (const float*)d_in[1];
    const int* ei_s = (const int*)d_in[2];
    const int* ei_t = (const int*)d_in[3];
    const int* xs_batch = (const int*)d_in[4];
    const int* xt_batch = (const int*)d_in[5];
    const float* W_s1 = (const float*)d_in[6];
    const float* a_src_s1 = (const float*)d_in[7];
    const float* a_dst_s1 = (const float*)d_in[8];
    const float* b_s1 = (const float*)d_in[9];
    const float* W_s2 = (const float*)d_in[10];
    const float* a_src_s2 = (const float*)d_in[11];
    const float* a_dst_s2 = (const float*)d_in[12];
    const float* b_s2 = (const float*)d_in[13];
    const float* W_t1 = (const float*)d_in[14];
    const float* a_src_t1 = (const float*)d_in[15];
    const float* a_dst_t1 = (const float*)d_in[16];
    const float* b_t1 = (const float*)d_in[17];
    const float* W_t2 = (const float*)d_in[18];
    const float* a_src_t2 = (const float*)d_in[19];
    const float* a_dst_t2 = (const float*)d_in[20];
    const float* b_t2 = (const float*)d_in[21];
    const float* lin_w = (const float*)d_in[22];
    const float* lin_b = (const float*)d_in[23];
    float* out = (float*)d_out;

    // workspace carve-up (floats)
    float* ws = (float*)d_ws;
    float* bufH = ws;                         // NN*128 (h1; later h2 [0..NN*64) and out2 [NN*64..NN*128))
    float* bufO = bufH + (size_t)NN * 128;    // NN*128 (out1 = conv2 input)
    float* al_s = bufO + (size_t)NN * 128;
    float* al_d = al_s + NN;
    float* es = al_d + NN;
    float* m_f = es + NN;
    float* denom = m_f + NN;
    unsigned* m_ord = (unsigned*)(denom + NN);
    float* pooled_s = (float*)(m_ord + NN);   // BB*64
    float* pooled_t = pooled_s + (size_t)BB * 64;
    float* cnt_s = pooled_t + (size_t)BB * 64;
    float* cnt_t = cnt_s + BB;

    // zero the pooled accumulators (atomically accumulated each call)
    hipMemsetAsync(pooled_s, 0, (size_t)(BB * 64 * 2 + BB * 2) * sizeof(float), stream);

    const int* src_s = ei_s;
    const int* dst_s = ei_s + EE;
    const int* src_t = ei_t;
    const int* dst_t = ei_t + EE;

    int node_wave_blocks = (NN * 64 + 255) / 256;

    // ----- branch s -----
    run_conv(x_s, DD, 128, W_s1, a_src_s1, a_dst_s1, b_s1, src_s, dst_s,
             bufH, bufO, al_s, al_d, es, m_f, denom, m_ord, stream);
    run_conv(bufO, 128, 64, W_s2, a_src_s2, a_dst_s2, b_s2, src_s, dst_s,
             bufH, bufH + (size_t)NN * 64, al_s, al_d, es, m_f, denom, m_ord, stream);
    pool_kernel<<<node_wave_blocks, 256, 0, stream>>>(bufH + (size_t)NN * 64, xs_batch, pooled_s, cnt_s, NN);

    // ----- branch t -----
    run_conv(x_t, DD, 128, W_t1, a_src_t1, a_dst_t1, b_t1, src_t, dst_t,
             bufH, bufO, al_s, al_d, es, m_f, denom, m_ord, stream);
    run_conv(bufO, 128, 64, W_t2, a_src_t2, a_dst_t2, b_t2, src_t, dst_t,
             bufH, bufH + (size_t)NN * 64, al_s, al_d, es, m_f, denom, m_ord, stream);
    pool_kernel<<<node_wave_blocks, 256, 0, stream>>>(bufH + (size_t)NN * 64, xt_batch, pooled_t, cnt_t, NN);

    // ----- head -----
    final_kernel<<<BB, 32, 0, stream>>>(pooled_s, pooled_t, cnt_s, cnt_t, lin_w, lin_b, out);
}

// Round 2
// 1929.622 us; speedup vs baseline: 1.8324x; 1.8324x over previous
//
#include <hip/hip_runtime.h>
#include <math.h>

#define NEG_SLOPE 0.2f

static const int NN = 100000;   // nodes per branch
static const int EE = 1600000;  // edges per branch
static const int BB = 512;      // graphs
static const int DD = 256;      // input dim

__device__ __forceinline__ float leaky(float x) { return x >= 0.f ? x : NEG_SLOPE * x; }

// ---------------- GEMM: C[M,N] = A[M,K] @ B[K,N], f32, BM=BN=64, BK=16 ----------------
__global__ void gemm64_kernel(const float* __restrict__ A, const float* __restrict__ B,
                              float* __restrict__ C, int M, int N, int K) {
    __shared__ float As[16][65];
    __shared__ float Bs[16][64];
    const int tid = threadIdx.x;
    const int tx = tid & 15, ty = tid >> 4;
    const int row0 = blockIdx.y * 64, col0 = blockIdx.x * 64;
    float acc[4][4] = {};
    for (int k0 = 0; k0 < K; k0 += 16) {
        #pragma unroll
        for (int i = 0; i < 4; i++) {
            int li = tid + i * 256;         // 0..1023
            int m = li >> 4, k = li & 15;
            int r = row0 + m;
            As[k][m] = (r < M) ? A[(size_t)r * K + k0 + k] : 0.f;
        }
        #pragma unroll
        for (int i = 0; i < 4; i++) {
            int li = tid + i * 256;
            int kk = li >> 6, n = li & 63;
            Bs[kk][n] = B[(size_t)(k0 + kk) * N + col0 + n];
        }
        __syncthreads();
        #pragma unroll
        for (int k = 0; k < 16; k++) {
            float am[4], bn[4];
            #pragma unroll
            for (int i = 0; i < 4; i++) am[i] = As[k][ty * 4 + i];
            #pragma unroll
            for (int j = 0; j < 4; j++) bn[j] = Bs[k][tx * 4 + j];
            #pragma unroll
            for (int i = 0; i < 4; i++)
                #pragma unroll
                for (int j = 0; j < 4; j++) acc[i][j] += am[i] * bn[j];
        }
        __syncthreads();
    }
    #pragma unroll
    for (int i = 0; i < 4; i++) {
        int r = row0 + ty * 4 + i;
        if (r >= M) continue;
        #pragma unroll
        for (int j = 0; j < 4; j++) C[(size_t)r * N + col0 + tx * 4 + j] = acc[i][j];
    }
}

// ---------------- per-node: al_s/al_d dots ----------------
template <int DOUT>
__global__ void node_al_kernel(const float* __restrict__ h,
                               const float* __restrict__ a_src, const float* __restrict__ a_dst,
                               float* __restrict__ al_s, float* __restrict__ al_d, int n) {
    int node = (blockIdx.x * blockDim.x + threadIdx.x) >> 6;
    int lane = threadIdx.x & 63;
    if (node >= n) return;
    const float* hp = h + (size_t)node * DOUT;
    float sa = 0.f, da = 0.f;
    #pragma unroll
    for (int c = lane; c < DOUT; c += 64) {
        float hv = hp[c];
        sa += hv * a_src[c];
        da += hv * a_dst[c];
    }
    #pragma unroll
    for (int off = 32; off > 0; off >>= 1) {
        sa += __shfl_down(sa, off);
        da += __shfl_down(da, off);
    }
    if (lane == 0) {
        al_s[node] = sa;
        al_d[node] = da;
    }
}

// ---------------- CSR build ----------------
__global__ void hist_kernel(const int* __restrict__ dst, int* __restrict__ deg, int ne) {
    int e = blockIdx.x * blockDim.x + threadIdx.x;
    if (e >= ne) return;
    atomicAdd(&deg[dst[e]], 1);
}

// single-block exclusive scan of deg[0..n) -> rowptr[0..n]
__global__ void scan_kernel(const int* __restrict__ deg, int* __restrict__ rowptr, int n) {
    __shared__ int part[256];
    const int t = threadIdx.x;
    const int chunk = (n + 255) / 256;
    const int b = t * chunk;
    const int e = min(b + chunk, n);
    int s = 0;
    for (int i = b; i < e; i++) s += deg[i];
    part[t] = s;
    __syncthreads();
    // Hillis-Steele inclusive scan over 256 entries
    for (int off = 1; off < 256; off <<= 1) {
        int u = (t >= off) ? part[t - off] : 0;
        __syncthreads();
        part[t] += u;
        __syncthreads();
    }
    int run = part[t] - s;  // exclusive prefix of this thread's chunk
    for (int i = b; i < e; i++) { rowptr[i] = run; run += deg[i]; }
    if (t == 255) rowptr[n] = run;
}

__global__ void fill_kernel(const int* __restrict__ src, const int* __restrict__ dst,
                            const int* __restrict__ rowptr, int* __restrict__ cursor,
                            int* __restrict__ col, int ne) {
    int e = blockIdx.x * blockDim.x + threadIdx.x;
    if (e >= ne) return;
    int d = dst[e];
    int pos = atomicAdd(&cursor[d], 1);
    col[rowptr[d] + pos] = src[e];
}

// ---------------- fused GAT aggregate: one wave per dst node, gather over CSR ----------------
template <int DOUT>
__global__ void gat_gather_kernel(const int* __restrict__ rowptr, const int* __restrict__ col,
                                  const float* __restrict__ al_s, const float* __restrict__ al_d,
                                  const float* __restrict__ h, const float* __restrict__ bias,
                                  float* __restrict__ out, int n) {
    int node = blockIdx.x * (blockDim.x >> 6) + (threadIdx.x >> 6);
    int lane = threadIdx.x & 63;
    if (node >= n) return;
    const int beg = rowptr[node], end = rowptr[node + 1];
    const float ald = al_d[node];
    const float e_self = leaky(al_s[node] + ald);

    // phase A: segment max (self loop included)
    float m = e_self;
    for (int i = beg + lane; i < end; i += 64) {
        int s = col[i];
        m = fmaxf(m, leaky(al_s[s] + ald));
    }
    #pragma unroll
    for (int off = 32; off > 0; off >>= 1) m = fmaxf(m, __shfl_xor(m, off));

    // phase B: accumulate sum(w) and sum(w * h[src])
    constexpr int CPL = DOUT / 64;   // cols per lane
    float acc[CPL] = {};
    float dsum = 0.f;
    for (int base = beg; base < end; base += 64) {
        int i = base + lane;
        float w = 0.f;
        int s = 0;
        if (i < end) {
            s = col[i];
            w = expf(leaky(al_s[s] + ald) - m);
        }
        dsum += w;
        int cnt = min(64, end - base);
        for (int j = 0; j < cnt; j++) {
            float wj = __shfl(w, j);
            int sj = __shfl(s, j);
            const float* hp = h + (size_t)sj * DOUT;
            #pragma unroll
            for (int q = 0; q < CPL; q++) acc[q] += wj * hp[lane + q * 64];
        }
    }
    #pragma unroll
    for (int off = 32; off > 0; off >>= 1) dsum += __shfl_xor(dsum, off);

    // self loop contribution + normalize + bias, single write
    float wself = expf(e_self - m);
    dsum += wself;
    float inv = 1.f / dsum;
    const float* hp = h + (size_t)node * DOUT;
    float* op = out + (size_t)node * DOUT;
    #pragma unroll
    for (int q = 0; q < CPL; q++) {
        int c = lane + q * 64;
        op[c] = bias[c] + (acc[q] + wself * hp[c]) * inv;
    }
}

// ---------------- mean-pool accumulation (one wave per node, DOUT=64) ----------------
__global__ void pool_kernel(const float* __restrict__ x, const int* __restrict__ batch,
                            float* __restrict__ pooled, float* __restrict__ cnt, int n) {
    int node = (blockIdx.x * blockDim.x + threadIdx.x) >> 6;
    int lane = threadIdx.x & 63;
    if (node >= n) return;
    int b = batch[node];
    atomicAdd(&pooled[(size_t)b * 64 + lane], x[(size_t)node * 64 + lane]);
    if (lane == 0) atomicAdd(&cnt[b], 1.f);
}

// ---------------- final: sigmoid((xs+xt)@lin_w + lin_b) ----------------
__global__ void final_kernel(const float* __restrict__ ps, const float* __restrict__ pt,
                             const float* __restrict__ cs, const float* __restrict__ ct,
                             const float* __restrict__ lw, const float* __restrict__ lb,
                             float* __restrict__ out) {
    int g = blockIdx.x;
    int c = threadIdx.x;
    if (c >= 27) return;
    float ics = 1.f / fmaxf(cs[g], 1.f);
    float ict = 1.f / fmaxf(ct[g], 1.f);
    float acc = lb[c];
    #pragma unroll 8
    for (int k = 0; k < 64; k++) {
        float xv = ps[g * 64 + k] * ics + pt[g * 64 + k] * ict;
        acc += xv * lw[k * 27 + c];
    }
    out[g * 27 + c] = 1.f / (1.f + expf(-acc));
}

// ---------------- one GAT conv layer (CSR prebuilt) ----------------
static void run_conv(const float* x, int din, int dout,
                     const float* W, const float* a_src, const float* a_dst, const float* bias,
                     const int* rowptr, const int* col,
                     float* h, float* out, float* al_s, float* al_d,
                     hipStream_t stream) {
    dim3 ggrid(dout / 64, (NN + 63) / 64);
    gemm64_kernel<<<ggrid, 256, 0, stream>>>(x, W, h, NN, dout, din);

    int node_wave_blocks = (NN * 64 + 255) / 256;
    int gather_blocks = (NN + 3) / 4;   // 4 waves (nodes) per 256-thread block

    if (dout == 128) {
        node_al_kernel<128><<<node_wave_blocks, 256, 0, stream>>>(h, a_src, a_dst, al_s, al_d, NN);
        gat_gather_kernel<128><<<gather_blocks, 256, 0, stream>>>(rowptr, col, al_s, al_d, h, bias, out, NN);
    } else {
        node_al_kernel<64><<<node_wave_blocks, 256, 0, stream>>>(h, a_src, a_dst, al_s, al_d, NN);
        gat_gather_kernel<64><<<gather_blocks, 256, 0, stream>>>(rowptr, col, al_s, al_d, h, bias, out, NN);
    }
}

static void build_csr(const int* src, const int* dst, int* rowptr, int* deg, int* col,
                      hipStream_t stream) {
    int edge_blocks = (EE + 255) / 256;
    hipMemsetAsync(deg, 0, NN * sizeof(int), stream);
    hist_kernel<<<edge_blocks, 256, 0, stream>>>(dst, deg, EE);
    scan_kernel<<<1, 256, 0, stream>>>(deg, rowptr, NN);
    hipMemsetAsync(deg, 0, NN * sizeof(int), stream);   // reuse as cursor
    fill_kernel<<<edge_blocks, 256, 0, stream>>>(src, dst, rowptr, deg, col, EE);
}

extern "C" void kernel_launch(void* const* d_in, const int* in_sizes, int n_in,
                              void* d_out, int out_size, void* d_ws, size_t ws_size,
                              hipStream_t stream) {
    const float* x_s = (const float*)d_in[0];
    const float* x_t = (const float*)d_in[1];
    const int* ei_s = (const int*)d_in[2];
    const int* ei_t = (const int*)d_in[3];
    const int* xs_batch = (const int*)d_in[4];
    const int* xt_batch = (const int*)d_in[5];
    const float* W_s1 = (const float*)d_in[6];
    const float* a_src_s1 = (const float*)d_in[7];
    const float* a_dst_s1 = (const float*)d_in[8];
    const float* b_s1 = (const float*)d_in[9];
    const float* W_s2 = (const float*)d_in[10];
    const float* a_src_s2 = (const float*)d_in[11];
    const float* a_dst_s2 = (const float*)d_in[12];
    const float* b_s2 = (const float*)d_in[13];
    const float* W_t1 = (const float*)d_in[14];
    const float* a_src_t1 = (const float*)d_in[15];
    const float* a_dst_t1 = (const float*)d_in[16];
    const float* b_t1 = (const float*)d_in[17];
    const float* W_t2 = (const float*)d_in[18];
    const float* a_src_t2 = (const float*)d_in[19];
    const float* a_dst_t2 = (const float*)d_in[20];
    const float* b_t2 = (const float*)d_in[21];
    const float* lin_w = (const float*)d_in[22];
    const float* lin_b = (const float*)d_in[23];
    float* out = (float*)d_out;

    // workspace carve-up
    float* ws = (float*)d_ws;
    float* bufH = ws;                          // NN*128
    float* bufO = bufH + (size_t)NN * 128;     // NN*128
    float* al_s = bufO + (size_t)NN * 128;     // NN
    float* al_d = al_s + NN;                   // NN
    float* pooled_s = al_d + NN;               // BB*64
    float* pooled_t = pooled_s + (size_t)BB * 64;
    float* cnt_s = pooled_t + (size_t)BB * 64; // BB
    float* cnt_t = cnt_s + BB;                 // BB
    int* rowptr = (int*)(cnt_t + BB);          // NN+1
    int* deg = rowptr + NN + 1;                // NN (also cursor)
    int* col = deg + NN;                       // EE

    hipMemsetAsync(pooled_s, 0, (size_t)(BB * 64 * 2 + BB * 2) * sizeof(float), stream);

    const int* src_s = ei_s;
    const int* dst_s = ei_s + EE;
    const int* src_t = ei_t;
    const int* dst_t = ei_t + EE;

    int node_wave_blocks = (NN * 64 + 255) / 256;

    // ----- branch s -----
    build_csr(src_s, dst_s, rowptr, deg, col, stream);
    run_conv(x_s, DD, 128, W_s1, a_src_s1, a_dst_s1, b_s1, rowptr, col,
             bufH, bufO, al_s, al_d, stream);
    run_conv(bufO, 128, 64, W_s2, a_src_s2, a_dst_s2, b_s2, rowptr, col,
             bufH, bufH + (size_t)NN * 64, al_s, al_d, stream);
    pool_kernel<<<node_wave_blocks, 256, 0, stream>>>(bufH + (size_t)NN * 64, xs_batch, pooled_s, cnt_s, NN);

    // ----- branch t -----
    build_csr(src_t, dst_t, rowptr, deg, col, stream);
    run_conv(x_t, DD, 128, W_t1, a_src_t1, a_dst_t1, b_t1, rowptr, col,
             bufH, bufO, al_s, al_d, stream);
    run_conv(bufO, 128, 64, W_t2, a_src_t2, a_dst_t2, b_t2, rowptr, col,
             bufH, bufH + (size_t)NN * 64, al_s, al_d, stream);
    pool_kernel<<<node_wave_blocks, 256, 0, stream>>>(bufH + (size_t)NN * 64, xt_batch, pooled_t, cnt_t, NN);

    // ----- head -----
    final_kernel<<<BB, 32, 0, stream>>>(pooled_s, pooled_t, cnt_s, cnt_t, lin_w, lin_b, out);
}

// Round 3
// 1628.468 us; speedup vs baseline: 2.1712x; 1.1849x over previous
//
#include <hip/hip_runtime.h>
#include <hip/hip_bf16.h>
#include <math.h>

#define NEG_SLOPE 0.2f

static const int NN = 100000;   // nodes per branch
static const int EE = 1600000;  // edges per branch
static const int BB = 512;      // graphs
static const int DD = 256;      // input dim

typedef __attribute__((ext_vector_type(8))) short bf16x8;
typedef __attribute__((ext_vector_type(4))) float f32x4;

__device__ __forceinline__ float leaky(float x) { return x >= 0.f ? x : NEG_SLOPE * x; }

__device__ __forceinline__ unsigned short f2b(float f) {
    __hip_bfloat16 h = __float2bfloat16(f);   // RNE
    return *reinterpret_cast<unsigned short*>(&h);
}

// ---------------- W^T cast: WT[n][k] = bf16(W[k][n]) ----------------
__global__ void wt_kernel(const float* __restrict__ W, unsigned short* __restrict__ WT,
                          int K, int N) {
    int idx = blockIdx.x * blockDim.x + threadIdx.x;
    if (idx >= K * N) return;
    int n = idx / K, k = idx - n * K;
    WT[idx] = f2b(W[(size_t)k * N + n]);
}

// ---------------- MFMA GEMM: C[M,N] = bf16(A[M,K]) @ bf16(W[K,N]), f32 accumulate ------
// A: f32 row-major (converted in-kernel). WT: bf16 [N][K] row-major. 4 waves/block,
// each wave computes a 16-row x N tile via mfma_f32_16x16x32_bf16.
template <int K, int N>
__global__ __launch_bounds__(256) void gemm_mfma_kernel(const float* __restrict__ A,
                                                        const unsigned short* __restrict__ WT,
                                                        float* __restrict__ C, int M) {
    constexpr int NT = N / 16;
    const int l = threadIdx.x & 63;
    const int w = threadIdx.x >> 6;
    const int rl = l & 15;        // A row / B col / D col within tile
    const int kh = l >> 4;        // k-block selector (8 elems each)
    const int row0 = blockIdx.x * 64 + w * 16;
    int rowc = min(row0 + rl, M - 1);           // clamped A row (garbage rows not stored)
    const float* Ap = A + (size_t)rowc * K + kh * 8;

    f32x4 acc[NT];
    #pragma unroll
    for (int t = 0; t < NT; t++) acc[t] = (f32x4){0.f, 0.f, 0.f, 0.f};

    for (int k0 = 0; k0 < K; k0 += 32) {
        float4 a0 = *(const float4*)(Ap + k0);
        float4 a1 = *(const float4*)(Ap + k0 + 4);
        union { bf16x8 v; unsigned short u[8]; } au;
        au.u[0] = f2b(a0.x); au.u[1] = f2b(a0.y); au.u[2] = f2b(a0.z); au.u[3] = f2b(a0.w);
        au.u[4] = f2b(a1.x); au.u[5] = f2b(a1.y); au.u[6] = f2b(a1.z); au.u[7] = f2b(a1.w);
        #pragma unroll
        for (int t = 0; t < NT; t++) {
            bf16x8 bv = *(const bf16x8*)(WT + (size_t)(t * 16 + rl) * K + k0 + kh * 8);
            acc[t] = __builtin_amdgcn_mfma_f32_16x16x32_bf16(au.v, bv, acc[t], 0, 0, 0);
        }
    }

    #pragma unroll
    for (int t = 0; t < NT; t++) {
        #pragma unroll
        for (int i = 0; i < 4; i++) {
            int r = row0 + kh * 4 + i;
            if (r < M) C[(size_t)r * N + t * 16 + rl] = acc[t][i];
        }
    }
}

// ---------------- per-node: al_s/al_d dots ----------------
template <int DOUT>
__global__ void node_al_kernel(const float* __restrict__ h,
                               const float* __restrict__ a_src, const float* __restrict__ a_dst,
                               float* __restrict__ al_s, float* __restrict__ al_d, int n) {
    int node = (blockIdx.x * blockDim.x + threadIdx.x) >> 6;
    int lane = threadIdx.x & 63;
    if (node >= n) return;
    const float* hp = h + (size_t)node * DOUT;
    float sa = 0.f, da = 0.f;
    #pragma unroll
    for (int c = lane; c < DOUT; c += 64) {
        float hv = hp[c];
        sa += hv * a_src[c];
        da += hv * a_dst[c];
    }
    #pragma unroll
    for (int off = 32; off > 0; off >>= 1) {
        sa += __shfl_down(sa, off);
        da += __shfl_down(da, off);
    }
    if (lane == 0) {
        al_s[node] = sa;
        al_d[node] = da;
    }
}

// ---------------- CSR / histogram helpers ----------------
__global__ void hist_kernel(const int* __restrict__ dst, int* __restrict__ deg, int ne) {
    int e = blockIdx.x * blockDim.x + threadIdx.x;
    if (e >= ne) return;
    atomicAdd(&deg[dst[e]], 1);
}

// single-block exclusive scan of deg[0..n) -> rowptr[0..n]
__global__ void scan_kernel(const int* __restrict__ deg, int* __restrict__ rowptr, int n) {
    __shared__ int part[256];
    const int t = threadIdx.x;
    const int chunk = (n + 255) / 256;
    const int b = t * chunk;
    const int e = min(b + chunk, n);
    int s = 0;
    for (int i = b; i < e; i++) s += deg[i];
    part[t] = s;
    __syncthreads();
    for (int off = 1; off < 256; off <<= 1) {
        int u = (t >= off) ? part[t - off] : 0;
        __syncthreads();
        part[t] += u;
        __syncthreads();
    }
    int run = part[t] - s;
    for (int i = b; i < e; i++) { rowptr[i] = run; run += deg[i]; }
    if (t == 255) rowptr[n] = run;
}

__global__ void fill_kernel(const int* __restrict__ src, const int* __restrict__ dst,
                            const int* __restrict__ rowptr, int* __restrict__ cursor,
                            int* __restrict__ col, int ne) {
    int e = blockIdx.x * blockDim.x + threadIdx.x;
    if (e >= ne) return;
    int d = dst[e];
    int pos = atomicAdd(&cursor[d], 1);
    col[rowptr[d] + pos] = src[e];
}

// ---------------- fused GAT aggregate: one wave per dst node, gather over CSR ----------------
template <int DOUT>
__global__ void gat_gather_kernel(const int* __restrict__ rowptr, const int* __restrict__ col,
                                  const float* __restrict__ al_s, const float* __restrict__ al_d,
                                  const float* __restrict__ h, const float* __restrict__ bias,
                                  float* __restrict__ out, int n) {
    int node = blockIdx.x * (blockDim.x >> 6) + (threadIdx.x >> 6);
    int lane = threadIdx.x & 63;
    if (node >= n) return;
    const int beg = rowptr[node], end = rowptr[node + 1];
    const float ald = al_d[node];
    const float e_self = leaky(al_s[node] + ald);

    float m = e_self;
    for (int i = beg + lane; i < end; i += 64) {
        int s = col[i];
        m = fmaxf(m, leaky(al_s[s] + ald));
    }
    #pragma unroll
    for (int off = 32; off > 0; off >>= 1) m = fmaxf(m, __shfl_xor(m, off));

    constexpr int CPL = DOUT / 64;
    float acc[CPL] = {};
    float dsum = 0.f;
    for (int base = beg; base < end; base += 64) {
        int i = base + lane;
        float w = 0.f;
        int s = 0;
        if (i < end) {
            s = col[i];
            w = expf(leaky(al_s[s] + ald) - m);
        }
        dsum += w;
        int cnt = min(64, end - base);
        for (int j = 0; j < cnt; j++) {
            float wj = __shfl(w, j);
            int sj = __shfl(s, j);
            const float* hp = h + (size_t)sj * DOUT;
            #pragma unroll
            for (int q = 0; q < CPL; q++) acc[q] += wj * hp[lane + q * 64];
        }
    }
    #pragma unroll
    for (int off = 32; off > 0; off >>= 1) dsum += __shfl_xor(dsum, off);

    float wself = expf(e_self - m);
    dsum += wself;
    float inv = 1.f / dsum;
    const float* hp = h + (size_t)node * DOUT;
    float* op = out + (size_t)node * DOUT;
    #pragma unroll
    for (int q = 0; q < CPL; q++) {
        int c = lane + q * 64;
        op[c] = bias[c] + (acc[q] + wself * hp[c]) * inv;
    }
}

// ---------------- segmented mean pool: one block per graph (batch is sorted) ----------------
__global__ void pool_seg_kernel(const float* __restrict__ x, const int* __restrict__ brow,
                                float* __restrict__ pooled) {
    __shared__ float red[4][64];
    int g = blockIdx.x;
    int lane = threadIdx.x & 63, w = threadIdx.x >> 6;
    int beg = brow[g], end = brow[g + 1];
    float acc = 0.f;
    for (int n = beg + w; n < end; n += 4)
        acc += x[(size_t)n * 64 + lane];
    red[w][lane] = acc;
    __syncthreads();
    if (w == 0) {
        float s = red[0][lane] + red[1][lane] + red[2][lane] + red[3][lane];
        float cnt = (float)(end - beg);
        pooled[(size_t)g * 64 + lane] = s / fmaxf(cnt, 1.f);
    }
}

// ---------------- final: sigmoid((xs+xt)@lin_w + lin_b), pooled already means ----------------
__global__ void final_kernel(const float* __restrict__ ps, const float* __restrict__ pt,
                             const float* __restrict__ lw, const float* __restrict__ lb,
                             float* __restrict__ out) {
    int g = blockIdx.x;
    int c = threadIdx.x;
    if (c >= 27) return;
    float acc = lb[c];
    #pragma unroll 8
    for (int k = 0; k < 64; k++) {
        float xv = ps[g * 64 + k] + pt[g * 64 + k];
        acc += xv * lw[k * 27 + c];
    }
    out[g * 27 + c] = 1.f / (1.f + expf(-acc));
}

// ---------------- one GAT conv layer (CSR prebuilt) ----------------
static void run_conv(const float* x, int din, int dout,
                     const float* W, const float* a_src, const float* a_dst, const float* bias,
                     const int* rowptr, const int* col,
                     float* h, float* out, float* al_s, float* al_d, unsigned short* WT,
                     hipStream_t stream) {
    wt_kernel<<<(din * dout + 255) / 256, 256, 0, stream>>>(W, WT, din, dout);
    int gblocks = (NN + 63) / 64;
    int node_wave_blocks = (NN * 64 + 255) / 256;
    int gather_blocks = (NN + 3) / 4;

    if (dout == 128) {
        gemm_mfma_kernel<256, 128><<<gblocks, 256, 0, stream>>>(x, WT, h, NN);
        node_al_kernel<128><<<node_wave_blocks, 256, 0, stream>>>(h, a_src, a_dst, al_s, al_d, NN);
        gat_gather_kernel<128><<<gather_blocks, 256, 0, stream>>>(rowptr, col, al_s, al_d, h, bias, out, NN);
    } else {
        gemm_mfma_kernel<128, 64><<<gblocks, 256, 0, stream>>>(x, WT, h, NN);
        node_al_kernel<64><<<node_wave_blocks, 256, 0, stream>>>(h, a_src, a_dst, al_s, al_d, NN);
        gat_gather_kernel<64><<<gather_blocks, 256, 0, stream>>>(rowptr, col, al_s, al_d, h, bias, out, NN);
    }
}

static void build_csr(const int* src, const int* dst, int* rowptr, int* deg, int* col,
                      hipStream_t stream) {
    int edge_blocks = (EE + 255) / 256;
    hipMemsetAsync(deg, 0, NN * sizeof(int), stream);
    hist_kernel<<<edge_blocks, 256, 0, stream>>>(dst, deg, EE);
    scan_kernel<<<1, 256, 0, stream>>>(deg, rowptr, NN);
    hipMemsetAsync(deg, 0, NN * sizeof(int), stream);   // reuse as cursor
    fill_kernel<<<edge_blocks, 256, 0, stream>>>(src, dst, rowptr, deg, col, EE);
}

static void run_pool(const float* x2, const int* batch, int* bcnt, int* brow, float* pooled,
                     hipStream_t stream) {
    hipMemsetAsync(bcnt, 0, BB * sizeof(int), stream);
    hist_kernel<<<(NN + 255) / 256, 256, 0, stream>>>(batch, bcnt, NN);
    scan_kernel<<<1, 256, 0, stream>>>(bcnt, brow, BB);
    pool_seg_kernel<<<BB, 256, 0, stream>>>(x2, brow, pooled);
}

extern "C" void kernel_launch(void* const* d_in, const int* in_sizes, int n_in,
                              void* d_out, int out_size, void* d_ws, size_t ws_size,
                              hipStream_t stream) {
    const float* x_s = (const float*)d_in[0];
    const float* x_t = (const float*)d_in[1];
    const int* ei_s = (const int*)d_in[2];
    const int* ei_t = (const int*)d_in[3];
    const int* xs_batch = (const int*)d_in[4];
    const int* xt_batch = (const int*)d_in[5];
    const float* W_s1 = (const float*)d_in[6];
    const float* a_src_s1 = (const float*)d_in[7];
    const float* a_dst_s1 = (const float*)d_in[8];
    const float* b_s1 = (const float*)d_in[9];
    const float* W_s2 = (const float*)d_in[10];
    const float* a_src_s2 = (const float*)d_in[11];
    const float* a_dst_s2 = (const float*)d_in[12];
    const float* b_s2 = (const float*)d_in[13];
    const float* W_t1 = (const float*)d_in[14];
    const float* a_src_t1 = (const float*)d_in[15];
    const float* a_dst_t1 = (const float*)d_in[16];
    const float* b_t1 = (const float*)d_in[17];
    const float* W_t2 = (const float*)d_in[18];
    const float* a_src_t2 = (const float*)d_in[19];
    const float* a_dst_t2 = (const float*)d_in[20];
    const float* b_t2 = (const float*)d_in[21];
    const float* lin_w = (const float*)d_in[22];
    const float* lin_b = (const float*)d_in[23];
    float* out = (float*)d_out;

    // workspace carve-up (float units; int arrays last so odd sizes don't break alignment)
    float* ws = (float*)d_ws;
    float* bufH = ws;                                   // NN*128
    float* bufO = bufH + (size_t)NN * 128;              // NN*128
    float* al_s = bufO + (size_t)NN * 128;              // NN
    float* al_d = al_s + NN;                            // NN
    float* pooled_s = al_d + NN;                        // BB*64
    float* pooled_t = pooled_s + (size_t)BB * 64;       // BB*64
    int* col = (int*)(pooled_t + (size_t)BB * 64);      // EE
    unsigned short* WT = (unsigned short*)(col + EE);   // 32768 (16B-aligned: offset mult of 4 floats)
    int* rowptr = (int*)(WT + 32768);                   // NN+1
    int* deg = rowptr + NN + 1;                         // NN
    int* brow = deg + NN;                               // BB+1
    int* bcnt = brow + BB + 1;                          // BB

    const int* src_s = ei_s;
    const int* dst_s = ei_s + EE;
    const int* src_t = ei_t;
    const int* dst_t = ei_t + EE;

    // ----- branch s -----
    build_csr(src_s, dst_s, rowptr, deg, col, stream);
    run_conv(x_s, DD, 128, W_s1, a_src_s1, a_dst_s1, b_s1, rowptr, col,
             bufH, bufO, al_s, al_d, WT, stream);
    run_conv(bufO, 128, 64, W_s2, a_src_s2, a_dst_s2, b_s2, rowptr, col,
             bufH, bufH + (size_t)NN * 64, al_s, al_d, WT, stream);
    run_pool(bufH + (size_t)NN * 64, xs_batch, bcnt, brow, pooled_s, stream);

    // ----- branch t -----
    build_csr(src_t, dst_t, rowptr, deg, col, stream);
    run_conv(x_t, DD, 128, W_t1, a_src_t1, a_dst_t1, b_t1, rowptr, col,
             bufH, bufO, al_s, al_d, WT, stream);
    run_conv(bufO, 128, 64, W_t2, a_src_t2, a_dst_t2, b_t2, rowptr, col,
             bufH, bufH + (size_t)NN * 64, al_s, al_d, WT, stream);
    run_pool(bufH + (size_t)NN * 64, xt_batch, bcnt, brow, pooled_t, stream);

    // ----- head -----
    final_kernel<<<BB, 32, 0, stream>>>(pooled_s, pooled_t, lin_w, lin_b, out);
}

// Round 4
// 1167.594 us; speedup vs baseline: 3.0282x; 1.3947x over previous
//
#include <hip/hip_runtime.h>
#include <hip/hip_bf16.h>
#include <math.h>

#define NEG_SLOPE 0.2f

static const int NN = 100000;   // nodes per branch
static const int EE = 1600000;  // edges per branch
static const int BB = 512;      // graphs
static const int DD = 256;      // input dim

typedef __attribute__((ext_vector_type(8))) short bf16x8;
typedef __attribute__((ext_vector_type(4))) float f32x4;

__device__ __forceinline__ float leaky(float x) { return x >= 0.f ? x : NEG_SLOPE * x; }

__device__ __forceinline__ unsigned short f2b(float f) {
    __hip_bfloat16 h = __float2bfloat16(f);   // RNE
    return *reinterpret_cast<unsigned short*>(&h);
}

// ---------------- W^T cast: WT[n][k] = bf16(W[k][n]) ----------------
__global__ void wt_kernel(const float* __restrict__ W, unsigned short* __restrict__ WT,
                          int K, int N) {
    int idx = blockIdx.x * blockDim.x + threadIdx.x;
    if (idx >= K * N) return;
    int n = idx / K, k = idx - n * K;
    WT[idx] = f2b(W[(size_t)k * N + n]);
}

// ---------------- MFMA GEMM: C[M,N] = bf16(A[M,K]) @ bf16(W[K,N]), f32 accumulate ------
template <int K, int N>
__global__ __launch_bounds__(256) void gemm_mfma_kernel(const float* __restrict__ A,
                                                        const unsigned short* __restrict__ WT,
                                                        float* __restrict__ C, int M) {
    constexpr int NT = N / 16;
    const int l = threadIdx.x & 63;
    const int w = threadIdx.x >> 6;
    const int rl = l & 15;        // A row / B col / D col within tile
    const int kh = l >> 4;        // k-block selector (8 elems each)
    const int row0 = blockIdx.x * 64 + w * 16;
    int rowc = min(row0 + rl, M - 1);
    const float* Ap = A + (size_t)rowc * K + kh * 8;

    f32x4 acc[NT];
    #pragma unroll
    for (int t = 0; t < NT; t++) acc[t] = (f32x4){0.f, 0.f, 0.f, 0.f};

    for (int k0 = 0; k0 < K; k0 += 32) {
        float4 a0 = *(const float4*)(Ap + k0);
        float4 a1 = *(const float4*)(Ap + k0 + 4);
        union { bf16x8 v; unsigned short u[8]; } au;
        au.u[0] = f2b(a0.x); au.u[1] = f2b(a0.y); au.u[2] = f2b(a0.z); au.u[3] = f2b(a0.w);
        au.u[4] = f2b(a1.x); au.u[5] = f2b(a1.y); au.u[6] = f2b(a1.z); au.u[7] = f2b(a1.w);
        #pragma unroll
        for (int t = 0; t < NT; t++) {
            bf16x8 bv = *(const bf16x8*)(WT + (size_t)(t * 16 + rl) * K + k0 + kh * 8);
            acc[t] = __builtin_amdgcn_mfma_f32_16x16x32_bf16(au.v, bv, acc[t], 0, 0, 0);
        }
    }

    #pragma unroll
    for (int t = 0; t < NT; t++) {
        #pragma unroll
        for (int i = 0; i < 4; i++) {
            int r = row0 + kh * 4 + i;
            if (r < M) C[(size_t)r * N + t * 16 + rl] = acc[t][i];
        }
    }
}

// ---------------- per-node: al_s/al_d dots ----------------
template <int DOUT>
__global__ void node_al_kernel(const float* __restrict__ h,
                               const float* __restrict__ a_src, const float* __restrict__ a_dst,
                               float* __restrict__ al_s, float* __restrict__ al_d, int n) {
    int node = (blockIdx.x * blockDim.x + threadIdx.x) >> 6;
    int lane = threadIdx.x & 63;
    if (node >= n) return;
    const float* hp = h + (size_t)node * DOUT;
    float sa = 0.f, da = 0.f;
    #pragma unroll
    for (int c = lane; c < DOUT; c += 64) {
        float hv = hp[c];
        sa += hv * a_src[c];
        da += hv * a_dst[c];
    }
    #pragma unroll
    for (int off = 32; off > 0; off >>= 1) {
        sa += __shfl_down(sa, off);
        da += __shfl_down(da, off);
    }
    if (lane == 0) {
        al_s[node] = sa;
        al_d[node] = da;
    }
}

// ---------------- CSR / histogram helpers ----------------
__global__ void hist_kernel(const int* __restrict__ dst, int* __restrict__ deg, int ne) {
    int e = blockIdx.x * blockDim.x + threadIdx.x;
    if (e >= ne) return;
    atomicAdd(&deg[dst[e]], 1);
}

// hierarchical scan, stage 1: per-block (1024-elem chunk) sums
__global__ void scan_sum_kernel(const int* __restrict__ deg, int* __restrict__ bsum, int n) {
    __shared__ int red[256];
    int t = threadIdx.x, b = blockIdx.x;
    int base = b * 1024;
    int lim = min(base + 1024, n);
    int s = 0;
    for (int i = base + t; i < lim; i += 256) s += deg[i];
    red[t] = s;
    __syncthreads();
    for (int off = 128; off > 0; off >>= 1) {
        if (t < off) red[t] += red[t + off];
        __syncthreads();
    }
    if (t == 0) bsum[b] = red[0];
}

// stage 2: single-block exclusive scan over G (<=256) block sums, in place
__global__ void scan_top_kernel(int* __restrict__ bsum, int G) {
    __shared__ int part[256];
    int t = threadIdx.x;
    int v = (t < G) ? bsum[t] : 0;
    part[t] = v;
    __syncthreads();
    for (int off = 1; off < 256; off <<= 1) {
        int u = (t >= off) ? part[t - off] : 0;
        __syncthreads();
        part[t] += u;
        __syncthreads();
    }
    if (t < G) bsum[t] = part[t] - v;
}

// stage 3: per-block exclusive scan of its chunk + block offset -> rowptr
__global__ void scan_write_kernel(const int* __restrict__ deg, const int* __restrict__ boff,
                                  int* __restrict__ rowptr, int n, int total) {
    __shared__ int part[256];
    __shared__ int carry;
    int t = threadIdx.x, b = blockIdx.x;
    if (t == 0) carry = boff[b];
    __syncthreads();
    #pragma unroll
    for (int tile = 0; tile < 4; tile++) {
        int i = b * 1024 + tile * 256 + t;
        int v = (i < n) ? deg[i] : 0;
        part[t] = v;
        __syncthreads();
        for (int off = 1; off < 256; off <<= 1) {
            int u = (t >= off) ? part[t - off] : 0;
            __syncthreads();
            part[t] += u;
            __syncthreads();
        }
        if (i < n) rowptr[i] = carry + part[t] - v;
        __syncthreads();
        if (t == 0) carry += part[255];
        __syncthreads();
    }
    if (b == 0 && t == 0) rowptr[n] = total;
}

__global__ void fill_kernel(const int* __restrict__ src, const int* __restrict__ dst,
                            const int* __restrict__ rowptr, int* __restrict__ cursor,
                            int* __restrict__ col, int ne) {
    int e = blockIdx.x * blockDim.x + threadIdx.x;
    if (e >= ne) return;
    int d = dst[e];
    int pos = atomicAdd(&cursor[d], 1);
    col[rowptr[d] + pos] = src[e];
}

// ---------------- graph boundaries via binary search (batch sorted) ----------------
__global__ void brow_kernel(const int* __restrict__ batch, int* __restrict__ brow, int n, int nb) {
    int g = blockIdx.x * blockDim.x + threadIdx.x;
    if (g > nb) return;
    int lo = 0, hi = n;
    while (lo < hi) {
        int mid = (lo + hi) >> 1;
        if (batch[mid] < g) lo = mid + 1; else hi = mid;
    }
    brow[g] = lo;   // first index with batch[i] >= g
}

// ---------------- fused GAT aggregate: one wave per dst node, gather over CSR ----------------
template <int DOUT>
__global__ void gat_gather_kernel(const int* __restrict__ rowptr, const int* __restrict__ col,
                                  const float* __restrict__ al_s, const float* __restrict__ al_d,
                                  const float* __restrict__ h, const float* __restrict__ bias,
                                  float* __restrict__ out, int n) {
    int node = blockIdx.x * (blockDim.x >> 6) + (threadIdx.x >> 6);
    int lane = threadIdx.x & 63;
    if (node >= n) return;
    const int beg = rowptr[node], end = rowptr[node + 1];
    const float ald = al_d[node];
    const float e_self = leaky(al_s[node] + ald);

    float m = e_self;
    for (int i = beg + lane; i < end; i += 64) {
        int s = col[i];
        m = fmaxf(m, leaky(al_s[s] + ald));
    }
    #pragma unroll
    for (int off = 32; off > 0; off >>= 1) m = fmaxf(m, __shfl_xor(m, off));

    constexpr int CPL = DOUT / 64;
    float acc[CPL] = {};
    float dsum = 0.f;
    for (int base = beg; base < end; base += 64) {
        int i = base + lane;
        float w = 0.f;
        int s = 0;
        if (i < end) {
            s = col[i];
            w = expf(leaky(al_s[s] + ald) - m);
        }
        dsum += w;
        int cnt = min(64, end - base);
        for (int j = 0; j < cnt; j++) {
            float wj = __shfl(w, j);
            int sj = __shfl(s, j);
            const float* hp = h + (size_t)sj * DOUT;
            #pragma unroll
            for (int q = 0; q < CPL; q++) acc[q] += wj * hp[lane + q * 64];
        }
    }
    #pragma unroll
    for (int off = 32; off > 0; off >>= 1) dsum += __shfl_xor(dsum, off);

    float wself = expf(e_self - m);
    dsum += wself;
    float inv = 1.f / dsum;
    const float* hp = h + (size_t)node * DOUT;
    float* op = out + (size_t)node * DOUT;
    #pragma unroll
    for (int q = 0; q < CPL; q++) {
        int c = lane + q * 64;
        op[c] = bias[c] + (acc[q] + wself * hp[c]) * inv;
    }
}

// ---------------- segmented mean pool: one block per graph ----------------
__global__ void pool_seg_kernel(const float* __restrict__ x, const int* __restrict__ brow,
                                float* __restrict__ pooled) {
    __shared__ float red[4][64];
    int g = blockIdx.x;
    int lane = threadIdx.x & 63, w = threadIdx.x >> 6;
    int beg = brow[g], end = brow[g + 1];
    float acc = 0.f;
    for (int n = beg + w; n < end; n += 4)
        acc += x[(size_t)n * 64 + lane];
    red[w][lane] = acc;
    __syncthreads();
    if (w == 0) {
        float s = red[0][lane] + red[1][lane] + red[2][lane] + red[3][lane];
        float cnt = (float)(end - beg);
        pooled[(size_t)g * 64 + lane] = s / fmaxf(cnt, 1.f);
    }
}

// ---------------- final: sigmoid((xs+xt)@lin_w + lin_b) ----------------
__global__ void final_kernel(const float* __restrict__ ps, const float* __restrict__ pt,
                             const float* __restrict__ lw, const float* __restrict__ lb,
                             float* __restrict__ out) {
    int g = blockIdx.x;
    int c = threadIdx.x;
    if (c >= 27) return;
    float acc = lb[c];
    #pragma unroll 8
    for (int k = 0; k < 64; k++) {
        float xv = ps[g * 64 + k] + pt[g * 64 + k];
        acc += xv * lw[k * 27 + c];
    }
    out[g * 27 + c] = 1.f / (1.f + expf(-acc));
}

// ---------------- one GAT conv layer (CSR prebuilt) ----------------
static void run_conv(const float* x, int din, int dout,
                     const float* W, const float* a_src, const float* a_dst, const float* bias,
                     const int* rowptr, const int* col,
                     float* h, float* out, float* al_s, float* al_d, unsigned short* WT,
                     hipStream_t stream) {
    wt_kernel<<<(din * dout + 255) / 256, 256, 0, stream>>>(W, WT, din, dout);
    int gblocks = (NN + 63) / 64;
    int node_wave_blocks = (NN * 64 + 255) / 256;
    int gather_blocks = (NN + 3) / 4;

    if (dout == 128) {
        gemm_mfma_kernel<256, 128><<<gblocks, 256, 0, stream>>>(x, WT, h, NN);
        node_al_kernel<128><<<node_wave_blocks, 256, 0, stream>>>(h, a_src, a_dst, al_s, al_d, NN);
        gat_gather_kernel<128><<<gather_blocks, 256, 0, stream>>>(rowptr, col, al_s, al_d, h, bias, out, NN);
    } else {
        gemm_mfma_kernel<128, 64><<<gblocks, 256, 0, stream>>>(x, WT, h, NN);
        node_al_kernel<64><<<node_wave_blocks, 256, 0, stream>>>(h, a_src, a_dst, al_s, al_d, NN);
        gat_gather_kernel<64><<<gather_blocks, 256, 0, stream>>>(rowptr, col, al_s, al_d, h, bias, out, NN);
    }
}

static void build_csr(const int* src, const int* dst, int* rowptr, int* deg, int* bsum, int* col,
                      hipStream_t stream) {
    int edge_blocks = (EE + 255) / 256;
    int G = (NN + 1023) / 1024;   // 98 blocks
    hipMemsetAsync(deg, 0, NN * sizeof(int), stream);
    hist_kernel<<<edge_blocks, 256, 0, stream>>>(dst, deg, EE);
    scan_sum_kernel<<<G, 256, 0, stream>>>(deg, bsum, NN);
    scan_top_kernel<<<1, 256, 0, stream>>>(bsum, G);
    scan_write_kernel<<<G, 256, 0, stream>>>(deg, bsum, rowptr, NN, EE);
    hipMemsetAsync(deg, 0, NN * sizeof(int), stream);   // reuse as cursor
    fill_kernel<<<edge_blocks, 256, 0, stream>>>(src, dst, rowptr, deg, col, EE);
}

static void run_pool(const float* x2, const int* batch, int* brow, float* pooled,
                     hipStream_t stream) {
    brow_kernel<<<(BB + 1 + 255) / 256, 256, 0, stream>>>(batch, brow, NN, BB);
    pool_seg_kernel<<<BB, 256, 0, stream>>>(x2, brow, pooled);
}

extern "C" void kernel_launch(void* const* d_in, const int* in_sizes, int n_in,
                              void* d_out, int out_size, void* d_ws, size_t ws_size,
                              hipStream_t stream) {
    const float* x_s = (const float*)d_in[0];
    const float* x_t = (const float*)d_in[1];
    const int* ei_s = (const int*)d_in[2];
    const int* ei_t = (const int*)d_in[3];
    const int* xs_batch = (const int*)d_in[4];
    const int* xt_batch = (const int*)d_in[5];
    const float* W_s1 = (const float*)d_in[6];
    const float* a_src_s1 = (const float*)d_in[7];
    const float* a_dst_s1 = (const float*)d_in[8];
    const float* b_s1 = (const float*)d_in[9];
    const float* W_s2 = (const float*)d_in[10];
    const float* a_src_s2 = (const float*)d_in[11];
    const float* a_dst_s2 = (const float*)d_in[12];
    const float* b_s2 = (const float*)d_in[13];
    const float* W_t1 = (const float*)d_in[14];
    const float* a_src_t1 = (const float*)d_in[15];
    const float* a_dst_t1 = (const float*)d_in[16];
    const float* b_t1 = (const float*)d_in[17];
    const float* W_t2 = (const float*)d_in[18];
    const float* a_src_t2 = (const float*)d_in[19];
    const float* a_dst_t2 = (const float*)d_in[20];
    const float* b_t2 = (const float*)d_in[21];
    const float* lin_w = (const float*)d_in[22];
    const float* lin_b = (const float*)d_in[23];
    float* out = (float*)d_out;

    // workspace carve-up
    float* ws = (float*)d_ws;
    float* bufH = ws;                                   // NN*128
    float* bufO = bufH + (size_t)NN * 128;              // NN*128
    float* al_s = bufO + (size_t)NN * 128;              // NN
    float* al_d = al_s + NN;                            // NN
    float* pooled_s = al_d + NN;                        // BB*64
    float* pooled_t = pooled_s + (size_t)BB * 64;       // BB*64
    int* col = (int*)(pooled_t + (size_t)BB * 64);      // EE
    unsigned short* WT = (unsigned short*)(col + EE);   // 32768 bf16
    int* rowptr = (int*)(WT + 32768);                   // NN+1
    int* deg = rowptr + NN + 1;                         // NN
    int* brow = deg + NN;                               // BB+1
    int* bsum = brow + BB + 1;                          // 128

    const int* src_s = ei_s;
    const int* dst_s = ei_s + EE;
    const int* src_t = ei_t;
    const int* dst_t = ei_t + EE;

    // ----- branch s -----
    build_csr(src_s, dst_s, rowptr, deg, bsum, col, stream);
    run_conv(x_s, DD, 128, W_s1, a_src_s1, a_dst_s1, b_s1, rowptr, col,
             bufH, bufO, al_s, al_d, WT, stream);
    run_conv(bufO, 128, 64, W_s2, a_src_s2, a_dst_s2, b_s2, rowptr, col,
             bufH, bufH + (size_t)NN * 64, al_s, al_d, WT, stream);
    run_pool(bufH + (size_t)NN * 64, xs_batch, brow, pooled_s, stream);

    // ----- branch t -----
    build_csr(src_t, dst_t, rowptr, deg, bsum, col, stream);
    run_conv(x_t, DD, 128, W_t1, a_src_t1, a_dst_t1, b_t1, rowptr, col,
             bufH, bufO, al_s, al_d, WT, stream);
    run_conv(bufO, 128, 64, W_t2, a_src_t2, a_dst_t2, b_t2, rowptr, col,
             bufH, bufH + (size_t)NN * 64, al_s, al_d, WT, stream);
    run_pool(bufH + (size_t)NN * 64, xt_batch, brow, pooled_t, stream);

    // ----- head -----
    final_kernel<<<BB, 32, 0, stream>>>(pooled_s, pooled_t, lin_w, lin_b, out);
}

// Round 5
// 1011.937 us; speedup vs baseline: 3.4940x; 1.1538x over previous
//
#include <hip/hip_runtime.h>
#include <hip/hip_bf16.h>
#include <math.h>

#define NEG_SLOPE 0.2f

static const int NN = 100000;   // nodes per branch
static const int EE = 1600000;  // edges per branch
static const int BB = 512;      // graphs
static const int DD = 256;      // input dim

typedef __attribute__((ext_vector_type(8))) short bf16x8;
typedef __attribute__((ext_vector_type(4))) float f32x4;

__device__ __forceinline__ float leaky(float x) { return x >= 0.f ? x : NEG_SLOPE * x; }

__device__ __forceinline__ unsigned short f2b(float f) {
    __hip_bfloat16 h = __float2bfloat16(f);   // RNE
    return *reinterpret_cast<unsigned short*>(&h);
}
__device__ __forceinline__ float b2f_lo(unsigned v) { return __uint_as_float(v << 16); }
__device__ __forceinline__ float b2f_hi(unsigned v) { return __uint_as_float(v & 0xFFFF0000u); }

// ---------------- W^T cast: WT[n][k] = bf16(W[k][n]) ----------------
__global__ void wt_kernel(const float* __restrict__ W, unsigned short* __restrict__ WT,
                          int K, int N) {
    int idx = blockIdx.x * blockDim.x + threadIdx.x;
    if (idx >= K * N) return;
    int n = idx / K, k = idx - n * K;
    WT[idx] = f2b(W[(size_t)k * N + n]);
}

// ---------------- h f32 -> packed bf16 pairs (dword = cols {2i, 2i+1}) ----------------
__global__ void hcast_kernel(const float* __restrict__ h, unsigned* __restrict__ hb, int ndw) {
    int i = blockIdx.x * blockDim.x + threadIdx.x;
    if (i >= ndw) return;
    float2 f = *(const float2*)(h + (size_t)i * 2);
    hb[i] = (unsigned)f2b(f.x) | ((unsigned)f2b(f.y) << 16);
}

// ---------------- MFMA GEMM: C[M,N] = bf16(A[M,K]) @ bf16(W[K,N]), f32 accumulate ------
template <int K, int N>
__global__ __launch_bounds__(256) void gemm_mfma_kernel(const float* __restrict__ A,
                                                        const unsigned short* __restrict__ WT,
                                                        float* __restrict__ C, int M) {
    constexpr int NT = N / 16;
    const int l = threadIdx.x & 63;
    const int w = threadIdx.x >> 6;
    const int rl = l & 15;
    const int kh = l >> 4;
    const int row0 = blockIdx.x * 64 + w * 16;
    int rowc = min(row0 + rl, M - 1);
    const float* Ap = A + (size_t)rowc * K + kh * 8;

    f32x4 acc[NT];
    #pragma unroll
    for (int t = 0; t < NT; t++) acc[t] = (f32x4){0.f, 0.f, 0.f, 0.f};

    for (int k0 = 0; k0 < K; k0 += 32) {
        float4 a0 = *(const float4*)(Ap + k0);
        float4 a1 = *(const float4*)(Ap + k0 + 4);
        union { bf16x8 v; unsigned short u[8]; } au;
        au.u[0] = f2b(a0.x); au.u[1] = f2b(a0.y); au.u[2] = f2b(a0.z); au.u[3] = f2b(a0.w);
        au.u[4] = f2b(a1.x); au.u[5] = f2b(a1.y); au.u[6] = f2b(a1.z); au.u[7] = f2b(a1.w);
        #pragma unroll
        for (int t = 0; t < NT; t++) {
            bf16x8 bv = *(const bf16x8*)(WT + (size_t)(t * 16 + rl) * K + k0 + kh * 8);
            acc[t] = __builtin_amdgcn_mfma_f32_16x16x32_bf16(au.v, bv, acc[t], 0, 0, 0);
        }
    }

    #pragma unroll
    for (int t = 0; t < NT; t++) {
        #pragma unroll
        for (int i = 0; i < 4; i++) {
            int r = row0 + kh * 4 + i;
            if (r < M) C[(size_t)r * N + t * 16 + rl] = acc[t][i];
        }
    }
}

// ---------------- per-node: al_s/al_d dots ----------------
template <int DOUT>
__global__ void node_al_kernel(const float* __restrict__ h,
                               const float* __restrict__ a_src, const float* __restrict__ a_dst,
                               float* __restrict__ al_s, float* __restrict__ al_d, int n) {
    int node = (blockIdx.x * blockDim.x + threadIdx.x) >> 6;
    int lane = threadIdx.x & 63;
    if (node >= n) return;
    const float* hp = h + (size_t)node * DOUT;
    float sa = 0.f, da = 0.f;
    #pragma unroll
    for (int c = lane; c < DOUT; c += 64) {
        float hv = hp[c];
        sa += hv * a_src[c];
        da += hv * a_dst[c];
    }
    #pragma unroll
    for (int off = 32; off > 0; off >>= 1) {
        sa += __shfl_down(sa, off);
        da += __shfl_down(da, off);
    }
    if (lane == 0) {
        al_s[node] = sa;
        al_d[node] = da;
    }
}

// ---------------- CSR / histogram helpers ----------------
__global__ void hist_kernel(const int* __restrict__ dst, int* __restrict__ deg, int ne) {
    int e = blockIdx.x * blockDim.x + threadIdx.x;
    if (e >= ne) return;
    atomicAdd(&deg[dst[e]], 1);
}

__global__ void scan_sum_kernel(const int* __restrict__ deg, int* __restrict__ bsum, int n) {
    __shared__ int red[256];
    int t = threadIdx.x, b = blockIdx.x;
    int base = b * 1024;
    int lim = min(base + 1024, n);
    int s = 0;
    for (int i = base + t; i < lim; i += 256) s += deg[i];
    red[t] = s;
    __syncthreads();
    for (int off = 128; off > 0; off >>= 1) {
        if (t < off) red[t] += red[t + off];
        __syncthreads();
    }
    if (t == 0) bsum[b] = red[0];
}

__global__ void scan_top_kernel(int* __restrict__ bsum, int G) {
    __shared__ int part[256];
    int t = threadIdx.x;
    int v = (t < G) ? bsum[t] : 0;
    part[t] = v;
    __syncthreads();
    for (int off = 1; off < 256; off <<= 1) {
        int u = (t >= off) ? part[t - off] : 0;
        __syncthreads();
        part[t] += u;
        __syncthreads();
    }
    if (t < G) bsum[t] = part[t] - v;
}

__global__ void scan_write_kernel(const int* __restrict__ deg, const int* __restrict__ boff,
                                  int* __restrict__ rowptr, int n, int total) {
    __shared__ int part[256];
    __shared__ int carry;
    int t = threadIdx.x, b = blockIdx.x;
    if (t == 0) carry = boff[b];
    __syncthreads();
    #pragma unroll
    for (int tile = 0; tile < 4; tile++) {
        int i = b * 1024 + tile * 256 + t;
        int v = (i < n) ? deg[i] : 0;
        part[t] = v;
        __syncthreads();
        for (int off = 1; off < 256; off <<= 1) {
            int u = (t >= off) ? part[t - off] : 0;
            __syncthreads();
            part[t] += u;
            __syncthreads();
        }
        if (i < n) rowptr[i] = carry + part[t] - v;
        __syncthreads();
        if (t == 0) carry += part[255];
        __syncthreads();
    }
    if (b == 0 && t == 0) rowptr[n] = total;
}

__global__ void fill_kernel(const int* __restrict__ src, const int* __restrict__ dst,
                            const int* __restrict__ rowptr, int* __restrict__ cursor,
                            int* __restrict__ col, int ne) {
    int e = blockIdx.x * blockDim.x + threadIdx.x;
    if (e >= ne) return;
    int d = dst[e];
    int pos = atomicAdd(&cursor[d], 1);
    col[rowptr[d] + pos] = src[e];
}

// ---------------- graph boundaries via binary search (batch sorted) ----------------
__global__ void brow_kernel(const int* __restrict__ batch, int* __restrict__ brow, int n, int nb) {
    int g = blockIdx.x * blockDim.x + threadIdx.x;
    if (g > nb) return;
    int lo = 0, hi = n;
    while (lo < hi) {
        int mid = (lo + hi) >> 1;
        if (batch[mid] < g) lo = mid + 1; else hi = mid;
    }
    brow[g] = lo;
}

// ---------------- fused GAT aggregate (no-max softmax, unrolled gather) ----------------
// BF=true: DOUT=128, gather from packed-bf16 hb (lane -> cols {2l,2l+1}).
// BF=false: f32 gathers, lane -> cols {l + q*64}.
template <int DOUT, bool BF>
__global__ void gat_gather_kernel(const int* __restrict__ rowptr, const int* __restrict__ col,
                                  const float* __restrict__ al_s, const float* __restrict__ al_d,
                                  const float* __restrict__ h, const unsigned* __restrict__ hb,
                                  const float* __restrict__ bias,
                                  float* __restrict__ out, int n) {
    int node = blockIdx.x * (blockDim.x >> 6) + (threadIdx.x >> 6);
    int lane = threadIdx.x & 63;
    if (node >= n) return;
    const int beg = rowptr[node], end = rowptr[node + 1];
    const float ald = al_d[node];
    const float e_self = leaky(al_s[node] + ald);

    constexpr int CPL = DOUT / 64;
    float acc0 = 0.f, acc1 = 0.f;
    float dsum = 0.f;

    for (int base = beg; base < end; base += 64) {
        int i = base + lane;
        float w = 0.f;
        int s = 0;
        if (i < end) {
            s = col[i];
            w = expf(leaky(al_s[s] + ald));   // no max shift: |e| <= ~7, exp safe in f32
        }
        dsum += w;
        int cnt = min(64, end - base);
        int j = 0;
        for (; j + 8 <= cnt; j += 8) {
            float wj[8]; int sj[8];
            #pragma unroll
            for (int u = 0; u < 8; u++) { wj[u] = __shfl(w, j + u); sj[u] = __shfl(s, j + u); }
            if constexpr (BF) {
                unsigned v[8];
                #pragma unroll
                for (int u = 0; u < 8; u++) v[u] = hb[(size_t)sj[u] * 64 + lane];
                #pragma unroll
                for (int u = 0; u < 8; u++) {
                    acc0 += wj[u] * b2f_lo(v[u]);
                    acc1 += wj[u] * b2f_hi(v[u]);
                }
            } else {
                float v0[8], v1[8];
                #pragma unroll
                for (int u = 0; u < 8; u++) {
                    const float* hp = h + (size_t)sj[u] * DOUT;
                    v0[u] = hp[lane];
                    if (CPL > 1) v1[u] = hp[lane + 64];
                }
                #pragma unroll
                for (int u = 0; u < 8; u++) {
                    acc0 += wj[u] * v0[u];
                    if (CPL > 1) acc1 += wj[u] * v1[u];
                }
            }
        }
        for (; j < cnt; j++) {
            float wj = __shfl(w, j);
            int sj = __shfl(s, j);
            if constexpr (BF) {
                unsigned v = hb[(size_t)sj * 64 + lane];
                acc0 += wj * b2f_lo(v);
                acc1 += wj * b2f_hi(v);
            } else {
                const float* hp = h + (size_t)sj * DOUT;
                acc0 += wj * hp[lane];
                if (CPL > 1) acc1 += wj * hp[lane + 64];
            }
        }
    }
    #pragma unroll
    for (int off = 32; off > 0; off >>= 1) dsum += __shfl_xor(dsum, off);

    float wself = expf(e_self);
    dsum += wself;
    float inv = 1.f / dsum;
    const float* hp = h + (size_t)node * DOUT;
    float* op = out + (size_t)node * DOUT;
    if constexpr (BF) {
        int c0 = 2 * lane, c1 = 2 * lane + 1;
        op[c0] = bias[c0] + (acc0 + wself * hp[c0]) * inv;
        op[c1] = bias[c1] + (acc1 + wself * hp[c1]) * inv;
    } else {
        op[lane] = bias[lane] + (acc0 + wself * hp[lane]) * inv;
        if (CPL > 1) op[lane + 64] = bias[lane + 64] + (acc1 + wself * hp[lane + 64]) * inv;
    }
}

// ---------------- segmented mean pool: one block per graph ----------------
__global__ void pool_seg_kernel(const float* __restrict__ x, const int* __restrict__ brow,
                                float* __restrict__ pooled) {
    __shared__ float red[4][64];
    int g = blockIdx.x;
    int lane = threadIdx.x & 63, w = threadIdx.x >> 6;
    int beg = brow[g], end = brow[g + 1];
    float acc = 0.f;
    for (int n = beg + w; n < end; n += 4)
        acc += x[(size_t)n * 64 + lane];
    red[w][lane] = acc;
    __syncthreads();
    if (w == 0) {
        float s = red[0][lane] + red[1][lane] + red[2][lane] + red[3][lane];
        float cnt = (float)(end - beg);
        pooled[(size_t)g * 64 + lane] = s / fmaxf(cnt, 1.f);
    }
}

// ---------------- final: sigmoid((xs+xt)@lin_w + lin_b) ----------------
__global__ void final_kernel(const float* __restrict__ ps, const float* __restrict__ pt,
                             const float* __restrict__ lw, const float* __restrict__ lb,
                             float* __restrict__ out) {
    int g = blockIdx.x;
    int c = threadIdx.x;
    if (c >= 27) return;
    float acc = lb[c];
    #pragma unroll 8
    for (int k = 0; k < 64; k++) {
        float xv = ps[g * 64 + k] + pt[g * 64 + k];
        acc += xv * lw[k * 27 + c];
    }
    out[g * 27 + c] = 1.f / (1.f + expf(-acc));
}

// ---------------- one GAT conv layer (CSR prebuilt) ----------------
static void run_conv(const float* x, int din, int dout,
                     const float* W, const float* a_src, const float* a_dst, const float* bias,
                     const int* rowptr, const int* col,
                     float* h, float* out, float* al_s, float* al_d, unsigned short* WT,
                     unsigned* hb, hipStream_t stream) {
    wt_kernel<<<(din * dout + 255) / 256, 256, 0, stream>>>(W, WT, din, dout);
    int gblocks = (NN + 63) / 64;
    int node_wave_blocks = (NN * 64 + 255) / 256;
    int gather_blocks = (NN + 3) / 4;

    if (dout == 128) {
        gemm_mfma_kernel<256, 128><<<gblocks, 256, 0, stream>>>(x, WT, h, NN);
        node_al_kernel<128><<<node_wave_blocks, 256, 0, stream>>>(h, a_src, a_dst, al_s, al_d, NN);
        if (hb) {
            hcast_kernel<<<(NN * 64 + 255) / 256, 256, 0, stream>>>(h, hb, NN * 64);
            gat_gather_kernel<128, true><<<gather_blocks, 256, 0, stream>>>(
                rowptr, col, al_s, al_d, h, hb, bias, out, NN);
        } else {
            gat_gather_kernel<128, false><<<gather_blocks, 256, 0, stream>>>(
                rowptr, col, al_s, al_d, h, nullptr, bias, out, NN);
        }
    } else {
        gemm_mfma_kernel<128, 64><<<gblocks, 256, 0, stream>>>(x, WT, h, NN);
        node_al_kernel<64><<<node_wave_blocks, 256, 0, stream>>>(h, a_src, a_dst, al_s, al_d, NN);
        gat_gather_kernel<64, false><<<gather_blocks, 256, 0, stream>>>(
            rowptr, col, al_s, al_d, h, nullptr, bias, out, NN);
    }
}

static void build_csr(const int* src, const int* dst, int* rowptr, int* deg, int* bsum, int* col,
                      hipStream_t stream) {
    int edge_blocks = (EE + 255) / 256;
    int G = (NN + 1023) / 1024;
    hipMemsetAsync(deg, 0, NN * sizeof(int), stream);
    hist_kernel<<<edge_blocks, 256, 0, stream>>>(dst, deg, EE);
    scan_sum_kernel<<<G, 256, 0, stream>>>(deg, bsum, NN);
    scan_top_kernel<<<1, 256, 0, stream>>>(bsum, G);
    scan_write_kernel<<<G, 256, 0, stream>>>(deg, bsum, rowptr, NN, EE);
    hipMemsetAsync(deg, 0, NN * sizeof(int), stream);
    fill_kernel<<<edge_blocks, 256, 0, stream>>>(src, dst, rowptr, deg, col, EE);
}

static void run_pool(const float* x2, const int* batch, int* brow, float* pooled,
                     hipStream_t stream) {
    brow_kernel<<<(BB + 1 + 255) / 256, 256, 0, stream>>>(batch, brow, NN, BB);
    pool_seg_kernel<<<BB, 256, 0, stream>>>(x2, brow, pooled);
}

extern "C" void kernel_launch(void* const* d_in, const int* in_sizes, int n_in,
                              void* d_out, int out_size, void* d_ws, size_t ws_size,
                              hipStream_t stream) {
    const float* x_s = (const float*)d_in[0];
    const float* x_t = (const float*)d_in[1];
    const int* ei_s = (const int*)d_in[2];
    const int* ei_t = (const int*)d_in[3];
    const int* xs_batch = (const int*)d_in[4];
    const int* xt_batch = (const int*)d_in[5];
    const float* W_s1 = (const float*)d_in[6];
    const float* a_src_s1 = (const float*)d_in[7];
    const float* a_dst_s1 = (const float*)d_in[8];
    const float* b_s1 = (const float*)d_in[9];
    const float* W_s2 = (const float*)d_in[10];
    const float* a_src_s2 = (const float*)d_in[11];
    const float* a_dst_s2 = (const float*)d_in[12];
    const float* b_s2 = (const float*)d_in[13];
    const float* W_t1 = (const float*)d_in[14];
    const float* a_src_t1 = (const float*)d_in[15];
    const float* a_dst_t1 = (const float*)d_in[16];
    const float* b_t1 = (const float*)d_in[17];
    const float* W_t2 = (const float*)d_in[18];
    const float* a_src_t2 = (const float*)d_in[19];
    const float* a_dst_t2 = (const float*)d_in[20];
    const float* b_t2 = (const float*)d_in[21];
    const float* lin_w = (const float*)d_in[22];
    const float* lin_b = (const float*)d_in[23];
    float* out = (float*)d_out;

    // workspace carve-up
    float* ws = (float*)d_ws;
    float* bufH = ws;                                   // NN*128
    float* bufO = bufH + (size_t)NN * 128;              // NN*128
    float* al_s = bufO + (size_t)NN * 128;              // NN
    float* al_d = al_s + NN;                            // NN
    float* pooled_s = al_d + NN;                        // BB*64
    float* pooled_t = pooled_s + (size_t)BB * 64;       // BB*64
    int* col = (int*)(pooled_t + (size_t)BB * 64);      // EE
    unsigned short* WT = (unsigned short*)(col + EE);   // 32768 bf16
    int* rowptr = (int*)(WT + 32768);                   // NN+1
    int* deg = rowptr + NN + 1;                         // NN
    int* brow = deg + NN;                               // BB+1
    int* bsum = brow + BB + 1;                          // 128
    unsigned* hb = (unsigned*)(bsum + 128);             // NN*64 dwords (bf16 pairs), optional

    size_t need = ((char*)(hb + (size_t)NN * 64)) - (char*)d_ws;
    unsigned* hb_use = (ws_size >= need) ? hb : nullptr;

    const int* src_s = ei_s;
    const int* dst_s = ei_s + EE;
    const int* src_t = ei_t;
    const int* dst_t = ei_t + EE;

    // ----- branch s -----
    build_csr(src_s, dst_s, rowptr, deg, bsum, col, stream);
    run_conv(x_s, DD, 128, W_s1, a_src_s1, a_dst_s1, b_s1, rowptr, col,
             bufH, bufO, al_s, al_d, WT, hb_use, stream);
    run_conv(bufO, 128, 64, W_s2, a_src_s2, a_dst_s2, b_s2, rowptr, col,
             bufH, bufH + (size_t)NN * 64, al_s, al_d, WT, nullptr, stream);
    run_pool(bufH + (size_t)NN * 64, xs_batch, brow, pooled_s, stream);

    // ----- branch t -----
    build_csr(src_t, dst_t, rowptr, deg, bsum, col, stream);
    run_conv(x_t, DD, 128, W_t1, a_src_t1, a_dst_t1, b_t1, rowptr, col,
             bufH, bufO, al_s, al_d, WT, hb_use, stream);
    run_conv(bufO, 128, 64, W_t2, a_src_t2, a_dst_t2, b_t2, rowptr, col,
             bufH, bufH + (size_t)NN * 64, al_s, al_d, WT, nullptr, stream);
    run_pool(bufH + (size_t)NN * 64, xt_batch, brow, pooled_t, stream);

    // ----- head -----
    final_kernel<<<BB, 32, 0, stream>>>(pooled_s, pooled_t, lin_w, lin_b, out);
}

// Round 6
// 936.770 us; speedup vs baseline: 3.7744x; 1.0802x over previous
//
#include <hip/hip_runtime.h>
#include <hip/hip_bf16.h>
#include <math.h>

#define NEG_SLOPE 0.2f

static const int NN = 100000;   // nodes per branch
static const int EE = 1600000;  // edges per branch
static const int BB = 512;      // graphs
static const int DD = 256;      // input dim

typedef __attribute__((ext_vector_type(8))) short bf16x8;
typedef __attribute__((ext_vector_type(4))) float f32x4;

__device__ __forceinline__ float leaky(float x) { return x >= 0.f ? x : NEG_SLOPE * x; }

__device__ __forceinline__ unsigned short f2b(float f) {
    __hip_bfloat16 h = __float2bfloat16(f);   // RNE
    return *reinterpret_cast<unsigned short*>(&h);
}
__device__ __forceinline__ float b2f_lo(unsigned v) { return __uint_as_float(v << 16); }
__device__ __forceinline__ float b2f_hi(unsigned v) { return __uint_as_float(v & 0xFFFF0000u); }

// ---------------- W^T cast: WT[n][k] = bf16(W[k][n]) ----------------
__global__ void wt_kernel(const float* __restrict__ W, unsigned short* __restrict__ WT,
                          int K, int N) {
    int idx = blockIdx.x * blockDim.x + threadIdx.x;
    if (idx >= K * N) return;
    int n = idx / K, k = idx - n * K;
    WT[idx] = f2b(W[(size_t)k * N + n]);
}

// ---- fused MFMA GEMM: C = bf16(A)@bf16(W); epilogue also emits packed-bf16 hb,
//      al_s = C·a_src, al_d = C·a_dst (per row). ----
template <int K, int N>
__global__ __launch_bounds__(256) void gemm_fused_kernel(const float* __restrict__ A,
                                                         const unsigned short* __restrict__ WT,
                                                         const float* __restrict__ a_src,
                                                         const float* __restrict__ a_dst,
                                                         float* __restrict__ C,
                                                         unsigned* __restrict__ hb,
                                                         float* __restrict__ al_s,
                                                         float* __restrict__ al_d, int M) {
    constexpr int NT = N / 16;
    const int l = threadIdx.x & 63;
    const int w = threadIdx.x >> 6;
    const int rl = l & 15;
    const int kh = l >> 4;
    const int row0 = blockIdx.x * 64 + w * 16;
    int rowc = min(row0 + rl, M - 1);
    const float* Ap = A + (size_t)rowc * K + kh * 8;

    f32x4 acc[NT];
    #pragma unroll
    for (int t = 0; t < NT; t++) acc[t] = (f32x4){0.f, 0.f, 0.f, 0.f};

    for (int k0 = 0; k0 < K; k0 += 32) {
        float4 a0 = *(const float4*)(Ap + k0);
        float4 a1 = *(const float4*)(Ap + k0 + 4);
        union { bf16x8 v; unsigned short u[8]; } au;
        au.u[0] = f2b(a0.x); au.u[1] = f2b(a0.y); au.u[2] = f2b(a0.z); au.u[3] = f2b(a0.w);
        au.u[4] = f2b(a1.x); au.u[5] = f2b(a1.y); au.u[6] = f2b(a1.z); au.u[7] = f2b(a1.w);
        #pragma unroll
        for (int t = 0; t < NT; t++) {
            bf16x8 bv = *(const bf16x8*)(WT + (size_t)(t * 16 + rl) * K + k0 + kh * 8);
            acc[t] = __builtin_amdgcn_mfma_f32_16x16x32_bf16(au.v, bv, acc[t], 0, 0, 0);
        }
    }

    // a-vector fragments for this lane's column slots
    float asr[NT], adr[NT];
    #pragma unroll
    for (int t = 0; t < NT; t++) { asr[t] = a_src[t * 16 + rl]; adr[t] = a_dst[t * 16 + rl]; }

    #pragma unroll
    for (int i = 0; i < 4; i++) {
        int r = row0 + kh * 4 + i;
        bool ok = (r < M);
        // al dots: reduce across the 16 lanes sharing kh
        float ps = 0.f, pd = 0.f;
        #pragma unroll
        for (int t = 0; t < NT; t++) { float v = acc[t][i]; ps += v * asr[t]; pd += v * adr[t]; }
        #pragma unroll
        for (int off = 1; off < 16; off <<= 1) {
            ps += __shfl_xor(ps, off);
            pd += __shfl_xor(pd, off);
        }
        if (ok && rl == 0) { al_s[r] = ps; al_d[r] = pd; }
        // C f32 + packed bf16
        #pragma unroll
        for (int t = 0; t < NT; t++) {
            float v = acc[t][i];
            float hi = __shfl_xor(v, 1);
            if (ok) {
                C[(size_t)r * N + t * 16 + rl] = v;
                if (!(rl & 1) && hb)
                    hb[(size_t)r * (N / 2) + (t * 16 + rl) / 2] =
                        (unsigned)f2b(v) | ((unsigned)f2b(hi) << 16);
            }
        }
    }
}

// ---------------- CSR / histogram helpers ----------------
__global__ void hist_kernel(const int* __restrict__ dst, int* __restrict__ deg, int ne) {
    int e = blockIdx.x * blockDim.x + threadIdx.x;
    if (e >= ne) return;
    atomicAdd(&deg[dst[e]], 1);
}

__global__ void scan_sum_kernel(const int* __restrict__ deg, int* __restrict__ bsum, int n) {
    __shared__ int red[256];
    int t = threadIdx.x, b = blockIdx.x;
    int base = b * 1024;
    int lim = min(base + 1024, n);
    int s = 0;
    for (int i = base + t; i < lim; i += 256) s += deg[i];
    red[t] = s;
    __syncthreads();
    for (int off = 128; off > 0; off >>= 1) {
        if (t < off) red[t] += red[t + off];
        __syncthreads();
    }
    if (t == 0) bsum[b] = red[0];
}

__global__ void scan_top_kernel(int* __restrict__ bsum, int G) {
    __shared__ int part[256];
    int t = threadIdx.x;
    int v = (t < G) ? bsum[t] : 0;
    part[t] = v;
    __syncthreads();
    for (int off = 1; off < 256; off <<= 1) {
        int u = (t >= off) ? part[t - off] : 0;
        __syncthreads();
        part[t] += u;
        __syncthreads();
    }
    if (t < G) bsum[t] = part[t] - v;
}

__global__ void scan_write_kernel(const int* __restrict__ deg, const int* __restrict__ boff,
                                  int* __restrict__ rowptr, int n, int total) {
    __shared__ int part[256];
    __shared__ int carry;
    int t = threadIdx.x, b = blockIdx.x;
    if (t == 0) carry = boff[b];
    __syncthreads();
    #pragma unroll
    for (int tile = 0; tile < 4; tile++) {
        int i = b * 1024 + tile * 256 + t;
        int v = (i < n) ? deg[i] : 0;
        part[t] = v;
        __syncthreads();
        for (int off = 1; off < 256; off <<= 1) {
            int u = (t >= off) ? part[t - off] : 0;
            __syncthreads();
            part[t] += u;
            __syncthreads();
        }
        if (i < n) rowptr[i] = carry + part[t] - v;
        __syncthreads();
        if (t == 0) carry += part[255];
        __syncthreads();
    }
    if (b == 0 && t == 0) rowptr[n] = total;
}

__global__ void fill_kernel(const int* __restrict__ src, const int* __restrict__ dst,
                            const int* __restrict__ rowptr, int* __restrict__ cursor,
                            int* __restrict__ col, int ne) {
    int e = blockIdx.x * blockDim.x + threadIdx.x;
    if (e >= ne) return;
    int d = dst[e];
    int pos = atomicAdd(&cursor[d], 1);
    col[rowptr[d] + pos] = src[e];
}

// ---------------- graph boundaries via binary search (batch sorted) ----------------
__global__ void brow_kernel(const int* __restrict__ batch, int* __restrict__ brow, int n, int nb) {
    int g = blockIdx.x * blockDim.x + threadIdx.x;
    if (g > nb) return;
    int lo = 0, hi = n;
    while (lo < hi) {
        int mid = (lo + hi) >> 1;
        if (batch[mid] < g) lo = mid + 1; else hi = mid;
    }
    brow[g] = lo;
}

// ---------------- GAT aggregate, D=128: one edge per wave-pass, packed-bf16 rows ------
__global__ void gat_gather128_kernel(const int* __restrict__ rowptr, const int* __restrict__ col,
                                     const float* __restrict__ al_s, const float* __restrict__ al_d,
                                     const float* __restrict__ h, const unsigned* __restrict__ hb,
                                     const float* __restrict__ bias,
                                     float* __restrict__ out, int n) {
    int node = blockIdx.x * 4 + (threadIdx.x >> 6);
    int lane = threadIdx.x & 63;
    if (node >= n) return;
    const int beg = rowptr[node], end = rowptr[node + 1];
    const float ald = al_d[node];
    const float e_self = leaky(al_s[node] + ald);

    float acc0 = 0.f, acc1 = 0.f, dsum = 0.f;
    for (int base = beg; base < end; base += 64) {
        int i = base + lane;
        float w = 0.f; int s = 0;
        if (i < end) {
            s = col[i];
            w = expf(leaky(al_s[s] + ald));   // no max shift: |e| small, f32-safe
        }
        dsum += w;
        int cnt = min(64, end - base);
        int j = 0;
        for (; j + 8 <= cnt; j += 8) {
            float wj[8]; int sj[8];
            #pragma unroll
            for (int u = 0; u < 8; u++) { wj[u] = __shfl(w, j + u); sj[u] = __shfl(s, j + u); }
            unsigned v[8];
            #pragma unroll
            for (int u = 0; u < 8; u++) v[u] = hb[(size_t)sj[u] * 64 + lane];
            #pragma unroll
            for (int u = 0; u < 8; u++) {
                acc0 += wj[u] * b2f_lo(v[u]);
                acc1 += wj[u] * b2f_hi(v[u]);
            }
        }
        for (; j < cnt; j++) {
            float wj = __shfl(w, j);
            int sj = __shfl(s, j);
            unsigned v = hb[(size_t)sj * 64 + lane];
            acc0 += wj * b2f_lo(v);
            acc1 += wj * b2f_hi(v);
        }
    }
    #pragma unroll
    for (int off = 32; off > 0; off >>= 1) dsum += __shfl_xor(dsum, off);

    float wself = expf(e_self);
    dsum += wself;
    float inv = 1.f / dsum;
    const float* hp = h + (size_t)node * 128;
    float* op = out + (size_t)node * 128;
    int c0 = 2 * lane, c1 = c0 + 1;
    op[c0] = bias[c0] + (acc0 + wself * hp[c0]) * inv;
    op[c1] = bias[c1] + (acc1 + wself * hp[c1]) * inv;
}

// ---------------- GAT aggregate, D=64: TWO edges per wave-pass, packed-bf16 rows ------
// Lanes 0-31 process edge j, lanes 32-63 edge j+1; each lane covers cols {2sl, 2sl+1}.
__global__ void gat_gather64_kernel(const int* __restrict__ rowptr, const int* __restrict__ col,
                                    const float* __restrict__ al_s, const float* __restrict__ al_d,
                                    const float* __restrict__ h, const unsigned* __restrict__ hb,
                                    const float* __restrict__ bias,
                                    float* __restrict__ out, int n) {
    int node = blockIdx.x * 4 + (threadIdx.x >> 6);
    int lane = threadIdx.x & 63;
    if (node >= n) return;
    const int sl = lane & 31, half = lane >> 5;
    const int beg = rowptr[node], end = rowptr[node + 1];
    const float ald = al_d[node];
    const float e_self = leaky(al_s[node] + ald);

    float acc0 = 0.f, acc1 = 0.f, dsum = 0.f;
    for (int base = beg; base < end; base += 64) {
        int i = base + lane;
        float w = 0.f; int s = 0;
        if (i < end) {
            s = col[i];
            w = expf(leaky(al_s[s] + ald));
        }
        dsum += w;
        int cnt = min(64, end - base);
        int j = 0;
        for (; j + 8 <= cnt; j += 8) {
            float wj[4]; int sj[4];
            #pragma unroll
            for (int u = 0; u < 4; u++) {
                int idx = j + 2 * u + half;
                wj[u] = __shfl(w, idx);
                sj[u] = __shfl(s, idx);
            }
            unsigned v[4];
            #pragma unroll
            for (int u = 0; u < 4; u++) v[u] = hb[(size_t)sj[u] * 32 + sl];
            #pragma unroll
            for (int u = 0; u < 4; u++) {
                acc0 += wj[u] * b2f_lo(v[u]);
                acc1 += wj[u] * b2f_hi(v[u]);
            }
        }
        for (; j < cnt; j += 2) {
            int idx = j + half;
            float wj = (idx < cnt) ? __shfl(w, idx) : 0.f;
            int sj = __shfl(s, idx < cnt ? idx : 0);
            unsigned v = hb[(size_t)sj * 32 + sl];
            acc0 += wj * b2f_lo(v);
            acc1 += wj * b2f_hi(v);
        }
    }
    // merge the two half-wave edge partitions (same cols on both halves)
    acc0 += __shfl_xor(acc0, 32);
    acc1 += __shfl_xor(acc1, 32);
    #pragma unroll
    for (int off = 32; off > 0; off >>= 1) dsum += __shfl_xor(dsum, off);

    float wself = expf(e_self);
    dsum += wself;
    float inv = 1.f / dsum;
    if (half == 0) {
        const float* hp = h + (size_t)node * 64;
        float* op = out + (size_t)node * 64;
        int c0 = 2 * sl, c1 = c0 + 1;
        op[c0] = bias[c0] + (acc0 + wself * hp[c0]) * inv;
        op[c1] = bias[c1] + (acc1 + wself * hp[c1]) * inv;
    }
}

// ---------------- segmented mean pool: one block per graph ----------------
__global__ void pool_seg_kernel(const float* __restrict__ x, const int* __restrict__ brow,
                                float* __restrict__ pooled) {
    __shared__ float red[4][64];
    int g = blockIdx.x;
    int lane = threadIdx.x & 63, w = threadIdx.x >> 6;
    int beg = brow[g], end = brow[g + 1];
    float acc = 0.f;
    for (int n = beg + w; n < end; n += 4)
        acc += x[(size_t)n * 64 + lane];
    red[w][lane] = acc;
    __syncthreads();
    if (w == 0) {
        float s = red[0][lane] + red[1][lane] + red[2][lane] + red[3][lane];
        float cnt = (float)(end - beg);
        pooled[(size_t)g * 64 + lane] = s / fmaxf(cnt, 1.f);
    }
}

// ---------------- final: sigmoid((xs+xt)@lin_w + lin_b) ----------------
__global__ void final_kernel(const float* __restrict__ ps, const float* __restrict__ pt,
                             const float* __restrict__ lw, const float* __restrict__ lb,
                             float* __restrict__ out) {
    int g = blockIdx.x;
    int c = threadIdx.x;
    if (c >= 27) return;
    float acc = lb[c];
    #pragma unroll 8
    for (int k = 0; k < 64; k++) {
        float xv = ps[g * 64 + k] + pt[g * 64 + k];
        acc += xv * lw[k * 27 + c];
    }
    out[g * 27 + c] = 1.f / (1.f + expf(-acc));
}

// ---------------- one GAT conv layer (CSR prebuilt) ----------------
static void run_conv(const float* x, int din, int dout,
                     const float* W, const float* a_src, const float* a_dst, const float* bias,
                     const int* rowptr, const int* col,
                     float* h, float* out, float* al_s, float* al_d, unsigned short* WT,
                     unsigned* hb, hipStream_t stream) {
    wt_kernel<<<(din * dout + 255) / 256, 256, 0, stream>>>(W, WT, din, dout);
    int gblocks = (NN + 63) / 64;
    int gather_blocks = (NN + 3) / 4;

    if (dout == 128) {
        gemm_fused_kernel<256, 128><<<gblocks, 256, 0, stream>>>(x, WT, a_src, a_dst,
                                                                 h, hb, al_s, al_d, NN);
        gat_gather128_kernel<<<gather_blocks, 256, 0, stream>>>(rowptr, col, al_s, al_d,
                                                                h, hb, bias, out, NN);
    } else {
        gemm_fused_kernel<128, 64><<<gblocks, 256, 0, stream>>>(x, WT, a_src, a_dst,
                                                                h, hb, al_s, al_d, NN);
        gat_gather64_kernel<<<gather_blocks, 256, 0, stream>>>(rowptr, col, al_s, al_d,
                                                               h, hb, bias, out, NN);
    }
}

static void build_csr(const int* src, const int* dst, int* rowptr, int* deg, int* bsum, int* col,
                      hipStream_t stream) {
    int edge_blocks = (EE + 255) / 256;
    int G = (NN + 1023) / 1024;
    hipMemsetAsync(deg, 0, NN * sizeof(int), stream);
    hist_kernel<<<edge_blocks, 256, 0, stream>>>(dst, deg, EE);
    scan_sum_kernel<<<G, 256, 0, stream>>>(deg, bsum, NN);
    scan_top_kernel<<<1, 256, 0, stream>>>(bsum, G);
    scan_write_kernel<<<G, 256, 0, stream>>>(deg, bsum, rowptr, NN, EE);
    hipMemsetAsync(deg, 0, NN * sizeof(int), stream);
    fill_kernel<<<edge_blocks, 256, 0, stream>>>(src, dst, rowptr, deg, col, EE);
}

static void run_pool(const float* x2, const int* batch, int* brow, float* pooled,
                     hipStream_t stream) {
    brow_kernel<<<(BB + 1 + 255) / 256, 256, 0, stream>>>(batch, brow, NN, BB);
    pool_seg_kernel<<<BB, 256, 0, stream>>>(x2, brow, pooled);
}

extern "C" void kernel_launch(void* const* d_in, const int* in_sizes, int n_in,
                              void* d_out, int out_size, void* d_ws, size_t ws_size,
                              hipStream_t stream) {
    const float* x_s = (const float*)d_in[0];
    const float* x_t = (const float*)d_in[1];
    const int* ei_s = (const int*)d_in[2];
    const int* ei_t = (const int*)d_in[3];
    const int* xs_batch = (const int*)d_in[4];
    const int* xt_batch = (const int*)d_in[5];
    const float* W_s1 = (const float*)d_in[6];
    const float* a_src_s1 = (const float*)d_in[7];
    const float* a_dst_s1 = (const float*)d_in[8];
    const float* b_s1 = (const float*)d_in[9];
    const float* W_s2 = (const float*)d_in[10];
    const float* a_src_s2 = (const float*)d_in[11];
    const float* a_dst_s2 = (const float*)d_in[12];
    const float* b_s2 = (const float*)d_in[13];
    const float* W_t1 = (const float*)d_in[14];
    const float* a_src_t1 = (const float*)d_in[15];
    const float* a_dst_t1 = (const float*)d_in[16];
    const float* b_t1 = (const float*)d_in[17];
    const float* W_t2 = (const float*)d_in[18];
    const float* a_src_t2 = (const float*)d_in[19];
    const float* a_dst_t2 = (const float*)d_in[20];
    const float* b_t2 = (const float*)d_in[21];
    const float* lin_w = (const float*)d_in[22];
    const float* lin_b = (const float*)d_in[23];
    float* out = (float*)d_out;

    // workspace carve-up
    float* ws = (float*)d_ws;
    float* bufH = ws;                                   // NN*128
    float* bufO = bufH + (size_t)NN * 128;              // NN*128
    float* al_s = bufO + (size_t)NN * 128;              // NN
    float* al_d = al_s + NN;                            // NN
    float* pooled_s = al_d + NN;                        // BB*64
    float* pooled_t = pooled_s + (size_t)BB * 64;       // BB*64
    int* col = (int*)(pooled_t + (size_t)BB * 64);      // EE
    unsigned short* WT = (unsigned short*)(col + EE);   // 32768 bf16
    int* rowptr = (int*)(WT + 32768);                   // NN+1
    int* deg = rowptr + NN + 1;                         // NN
    int* brow = deg + NN;                               // BB+1
    int* bsum = brow + BB + 1;                          // 128
    unsigned* hb = (unsigned*)(bsum + 128);             // NN*64 dwords (bf16 pairs)

    const int* src_s = ei_s;
    const int* dst_s = ei_s + EE;
    const int* src_t = ei_t;
    const int* dst_t = ei_t + EE;

    // ----- branch s -----
    build_csr(src_s, dst_s, rowptr, deg, bsum, col, stream);
    run_conv(x_s, DD, 128, W_s1, a_src_s1, a_dst_s1, b_s1, rowptr, col,
             bufH, bufO, al_s, al_d, WT, hb, stream);
    run_conv(bufO, 128, 64, W_s2, a_src_s2, a_dst_s2, b_s2, rowptr, col,
             bufH, bufH + (size_t)NN * 64, al_s, al_d, WT, hb, stream);
    run_pool(bufH + (size_t)NN * 64, xs_batch, brow, pooled_s, stream);

    // ----- branch t -----
    build_csr(src_t, dst_t, rowptr, deg, bsum, col, stream);
    run_conv(x_t, DD, 128, W_t1, a_src_t1, a_dst_t1, b_t1, rowptr, col,
             bufH, bufO, al_s, al_d, WT, hb, stream);
    run_conv(bufO, 128, 64, W_t2, a_src_t2, a_dst_t2, b_t2, rowptr, col,
             bufH, bufH + (size_t)NN * 64, al_s, al_d, WT, hb, stream);
    run_pool(bufH + (size_t)NN * 64, xt_batch, brow, pooled_t, stream);

    // ----- head -----
    final_kernel<<<BB, 32, 0, stream>>>(pooled_s, pooled_t, lin_w, lin_b, out);
}

// Round 7
// 805.137 us; speedup vs baseline: 4.3915x; 1.1635x over previous
//
#include <hip/hip_runtime.h>
#include <hip/hip_bf16.h>
#include <math.h>

#define NEG_SLOPE 0.2f

static const int NN = 100000;   // nodes per branch
static const int EE = 1600000;  // edges per branch
static const int BB = 512;      // graphs
static const int DD = 256;      // input dim

typedef __attribute__((ext_vector_type(8))) short bf16x8;
typedef __attribute__((ext_vector_type(4))) float f32x4;

__device__ __forceinline__ float leaky(float x) { return x >= 0.f ? x : NEG_SLOPE * x; }

__device__ __forceinline__ unsigned short f2b(float f) {
    __hip_bfloat16 h = __float2bfloat16(f);   // RNE
    return *reinterpret_cast<unsigned short*>(&h);
}
__device__ __forceinline__ float b2f_lo(unsigned v) { return __uint_as_float(v << 16); }
__device__ __forceinline__ float b2f_hi(unsigned v) { return __uint_as_float(v & 0xFFFF0000u); }
__device__ __forceinline__ unsigned packb(float a, float b) {
    return (unsigned)f2b(a) | ((unsigned)f2b(b) << 16);
}

// ---------------- W^T cast: WT[n][k] = bf16(W[k][n]) ----------------
__global__ void wt_kernel(const float* __restrict__ W, unsigned short* __restrict__ WT,
                          int K, int N) {
    int idx = blockIdx.x * blockDim.x + threadIdx.x;
    if (idx >= K * N) return;
    int n = idx / K, k = idx - n * K;
    WT[idx] = f2b(W[(size_t)k * N + n]);
}

// ---- fused MFMA GEMM: hb = packed-bf16(bf16(A)@bf16(W)); al_s/al_d = h·a_src / h·a_dst.
//      No f32 C. 32 rows/wave, 128 rows/block. ABF: A is bf16 (ushort) instead of f32. ----
template <int K, int N, bool ABF>
__global__ __launch_bounds__(256, 2) void gemm_fused_kernel(const void* __restrict__ Av,
                                                            const unsigned short* __restrict__ WT,
                                                            const float* __restrict__ a_src,
                                                            const float* __restrict__ a_dst,
                                                            unsigned* __restrict__ hb,
                                                            float* __restrict__ al_s,
                                                            float* __restrict__ al_d, int M) {
    constexpr int NT = N / 16;
    const int l = threadIdx.x & 63;
    const int w = threadIdx.x >> 6;
    const int rl = l & 15;
    const int kh = l >> 4;
    const int wrow0 = blockIdx.x * 128 + w * 32;
    const int r0 = min(wrow0 + rl, M - 1);
    const int r1 = min(wrow0 + 16 + rl, M - 1);

    f32x4 acc[2][NT];
    #pragma unroll
    for (int g = 0; g < 2; g++)
        #pragma unroll
        for (int t = 0; t < NT; t++) acc[g][t] = (f32x4){0.f, 0.f, 0.f, 0.f};

    #pragma unroll
    for (int k0 = 0; k0 < K; k0 += 32) {
        bf16x8 a0v, a1v;
        if constexpr (ABF) {
            const unsigned short* A = (const unsigned short*)Av;
            a0v = *(const bf16x8*)(A + (size_t)r0 * K + k0 + kh * 8);
            a1v = *(const bf16x8*)(A + (size_t)r1 * K + k0 + kh * 8);
        } else {
            const float* A = (const float*)Av;
            float4 x0 = *(const float4*)(A + (size_t)r0 * K + k0 + kh * 8);
            float4 x1 = *(const float4*)(A + (size_t)r0 * K + k0 + kh * 8 + 4);
            float4 y0 = *(const float4*)(A + (size_t)r1 * K + k0 + kh * 8);
            float4 y1 = *(const float4*)(A + (size_t)r1 * K + k0 + kh * 8 + 4);
            union { bf16x8 v; unsigned short u[8]; } au, bu;
            au.u[0] = f2b(x0.x); au.u[1] = f2b(x0.y); au.u[2] = f2b(x0.z); au.u[3] = f2b(x0.w);
            au.u[4] = f2b(x1.x); au.u[5] = f2b(x1.y); au.u[6] = f2b(x1.z); au.u[7] = f2b(x1.w);
            bu.u[0] = f2b(y0.x); bu.u[1] = f2b(y0.y); bu.u[2] = f2b(y0.z); bu.u[3] = f2b(y0.w);
            bu.u[4] = f2b(y1.x); bu.u[5] = f2b(y1.y); bu.u[6] = f2b(y1.z); bu.u[7] = f2b(y1.w);
            a0v = au.v; a1v = bu.v;
        }
        #pragma unroll
        for (int t = 0; t < NT; t++) {
            bf16x8 bv = *(const bf16x8*)(WT + (size_t)(t * 16 + rl) * K + k0 + kh * 8);
            acc[0][t] = __builtin_amdgcn_mfma_f32_16x16x32_bf16(a0v, bv, acc[0][t], 0, 0, 0);
            acc[1][t] = __builtin_amdgcn_mfma_f32_16x16x32_bf16(a1v, bv, acc[1][t], 0, 0, 0);
        }
    }

    float asr[NT], adr[NT];
    #pragma unroll
    for (int t = 0; t < NT; t++) { asr[t] = a_src[t * 16 + rl]; adr[t] = a_dst[t * 16 + rl]; }

    #pragma unroll
    for (int rg = 0; rg < 2; rg++) {
        #pragma unroll
        for (int i = 0; i < 4; i++) {
            int r = wrow0 + rg * 16 + kh * 4 + i;
            bool ok = (r < M);
            float ps = 0.f, pd = 0.f;
            #pragma unroll
            for (int t = 0; t < NT; t++) {
                float v = acc[rg][t][i];
                ps += v * asr[t];
                pd += v * adr[t];
            }
            #pragma unroll
            for (int off = 1; off < 16; off <<= 1) {
                ps += __shfl_xor(ps, off);
                pd += __shfl_xor(pd, off);
            }
            if (ok && rl == 0) { al_s[r] = ps; al_d[r] = pd; }
            #pragma unroll
            for (int t = 0; t < NT; t++) {
                float v = acc[rg][t][i];
                float hi = __shfl_xor(v, 1);
                if (ok && !(rl & 1))
                    hb[(size_t)r * (N / 2) + (t * 16 + rl) / 2] = packb(v, hi);
            }
        }
    }
}

// ---------------- CSR / histogram helpers ----------------
__global__ void hist_kernel(const int* __restrict__ dst, int* __restrict__ deg, int ne) {
    int e = blockIdx.x * blockDim.x + threadIdx.x;
    if (e >= ne) return;
    atomicAdd(&deg[dst[e]], 1);
}

__global__ void scan_sum_kernel(const int* __restrict__ deg, int* __restrict__ bsum, int n) {
    __shared__ int red[256];
    int t = threadIdx.x, b = blockIdx.x;
    int base = b * 1024;
    int lim = min(base + 1024, n);
    int s = 0;
    for (int i = base + t; i < lim; i += 256) s += deg[i];
    red[t] = s;
    __syncthreads();
    for (int off = 128; off > 0; off >>= 1) {
        if (t < off) red[t] += red[t + off];
        __syncthreads();
    }
    if (t == 0) bsum[b] = red[0];
}

__global__ void scan_top_kernel(int* __restrict__ bsum, int G) {
    __shared__ int part[256];
    int t = threadIdx.x;
    int v = (t < G) ? bsum[t] : 0;
    part[t] = v;
    __syncthreads();
    for (int off = 1; off < 256; off <<= 1) {
        int u = (t >= off) ? part[t - off] : 0;
        __syncthreads();
        part[t] += u;
        __syncthreads();
    }
    if (t < G) bsum[t] = part[t] - v;
}

__global__ void scan_write_kernel(const int* __restrict__ deg, const int* __restrict__ boff,
                                  int* __restrict__ rowptr, int n, int total) {
    __shared__ int part[256];
    __shared__ int carry;
    int t = threadIdx.x, b = blockIdx.x;
    if (t == 0) carry = boff[b];
    __syncthreads();
    #pragma unroll
    for (int tile = 0; tile < 4; tile++) {
        int i = b * 1024 + tile * 256 + t;
        int v = (i < n) ? deg[i] : 0;
        part[t] = v;
        __syncthreads();
        for (int off = 1; off < 256; off <<= 1) {
            int u = (t >= off) ? part[t - off] : 0;
            __syncthreads();
            part[t] += u;
            __syncthreads();
        }
        if (i < n) rowptr[i] = carry + part[t] - v;
        __syncthreads();
        if (t == 0) carry += part[255];
        __syncthreads();
    }
    if (b == 0 && t == 0) rowptr[n] = total;
}

__global__ void fill_kernel(const int* __restrict__ src, const int* __restrict__ dst,
                            const int* __restrict__ rowptr, int* __restrict__ cursor,
                            int* __restrict__ col, int ne) {
    int e = blockIdx.x * blockDim.x + threadIdx.x;
    if (e >= ne) return;
    int d = dst[e];
    int pos = atomicAdd(&cursor[d], 1);
    col[rowptr[d] + pos] = src[e];
}

// ---------------- graph boundaries via binary search (batch sorted) ----------------
__global__ void brow_kernel(const int* __restrict__ batch, int* __restrict__ brow, int n, int nb) {
    int g = blockIdx.x * blockDim.x + threadIdx.x;
    if (g > nb) return;
    int lo = 0, hi = n;
    while (lo < hi) {
        int mid = (lo + hi) >> 1;
        if (batch[mid] < g) lo = mid + 1; else hi = mid;
    }
    brow[g] = lo;
}

// ---------------- GAT aggregate, D=128: one edge per wave-pass; bf16 in, bf16 out ------
__global__ void gat_gather128_kernel(const int* __restrict__ rowptr, const int* __restrict__ col,
                                     const float* __restrict__ al_s, const float* __restrict__ al_d,
                                     const unsigned* __restrict__ hb,
                                     const float* __restrict__ bias,
                                     unsigned* __restrict__ outb, int n) {
    int node = blockIdx.x * 4 + (threadIdx.x >> 6);
    int lane = threadIdx.x & 63;
    if (node >= n) return;
    const int beg = rowptr[node], end = rowptr[node + 1];
    const float ald = al_d[node];
    const float e_self = leaky(al_s[node] + ald);

    float acc0 = 0.f, acc1 = 0.f, dsum = 0.f;
    for (int base = beg; base < end; base += 64) {
        int i = base + lane;
        float w = 0.f; int s = 0;
        if (i < end) {
            s = col[i];
            w = expf(leaky(al_s[s] + ald));   // no max shift: |e| small, f32-safe
        }
        dsum += w;
        int cnt = min(64, end - base);
        int j = 0;
        for (; j + 8 <= cnt; j += 8) {
            float wj[8]; int sj[8];
            #pragma unroll
            for (int u = 0; u < 8; u++) { wj[u] = __shfl(w, j + u); sj[u] = __shfl(s, j + u); }
            unsigned v[8];
            #pragma unroll
            for (int u = 0; u < 8; u++) v[u] = hb[(size_t)sj[u] * 64 + lane];
            #pragma unroll
            for (int u = 0; u < 8; u++) {
                acc0 += wj[u] * b2f_lo(v[u]);
                acc1 += wj[u] * b2f_hi(v[u]);
            }
        }
        for (; j < cnt; j++) {
            float wj = __shfl(w, j);
            int sj = __shfl(s, j);
            unsigned v = hb[(size_t)sj * 64 + lane];
            acc0 += wj * b2f_lo(v);
            acc1 += wj * b2f_hi(v);
        }
    }
    #pragma unroll
    for (int off = 32; off > 0; off >>= 1) dsum += __shfl_xor(dsum, off);

    float wself = expf(e_self);
    dsum += wself;
    float inv = 1.f / dsum;
    unsigned sv = hb[(size_t)node * 64 + lane];
    int c0 = 2 * lane, c1 = c0 + 1;
    float o0 = bias[c0] + (acc0 + wself * b2f_lo(sv)) * inv;
    float o1 = bias[c1] + (acc1 + wself * b2f_hi(sv)) * inv;
    outb[(size_t)node * 64 + lane] = packb(o0, o1);
}

// ---------------- GAT aggregate, D=64: TWO edges per wave-pass; bf16 in, f32 out ------
__global__ void gat_gather64_kernel(const int* __restrict__ rowptr, const int* __restrict__ col,
                                    const float* __restrict__ al_s, const float* __restrict__ al_d,
                                    const unsigned* __restrict__ hb,
                                    const float* __restrict__ bias,
                                    float* __restrict__ out, int n) {
    int node = blockIdx.x * 4 + (threadIdx.x >> 6);
    int lane = threadIdx.x & 63;
    if (node >= n) return;
    const int sl = lane & 31, half = lane >> 5;
    const int beg = rowptr[node], end = rowptr[node + 1];
    const float ald = al_d[node];
    const float e_self = leaky(al_s[node] + ald);

    float acc0 = 0.f, acc1 = 0.f, dsum = 0.f;
    for (int base = beg; base < end; base += 64) {
        int i = base + lane;
        float w = 0.f; int s = 0;
        if (i < end) {
            s = col[i];
            w = expf(leaky(al_s[s] + ald));
        }
        dsum += w;
        int cnt = min(64, end - base);
        int j = 0;
        for (; j + 8 <= cnt; j += 8) {
            float wj[4]; int sj[4];
            #pragma unroll
            for (int u = 0; u < 4; u++) {
                int idx = j + 2 * u + half;
                wj[u] = __shfl(w, idx);
                sj[u] = __shfl(s, idx);
            }
            unsigned v[4];
            #pragma unroll
            for (int u = 0; u < 4; u++) v[u] = hb[(size_t)sj[u] * 32 + sl];
            #pragma unroll
            for (int u = 0; u < 4; u++) {
                acc0 += wj[u] * b2f_lo(v[u]);
                acc1 += wj[u] * b2f_hi(v[u]);
            }
        }
        for (; j < cnt; j += 2) {
            int idx = j + half;
            float wj = (idx < cnt) ? __shfl(w, idx) : 0.f;
            int sj = __shfl(s, idx < cnt ? idx : 0);
            unsigned v = hb[(size_t)sj * 32 + sl];
            acc0 += wj * b2f_lo(v);
            acc1 += wj * b2f_hi(v);
        }
    }
    acc0 += __shfl_xor(acc0, 32);
    acc1 += __shfl_xor(acc1, 32);
    #pragma unroll
    for (int off = 32; off > 0; off >>= 1) dsum += __shfl_xor(dsum, off);

    float wself = expf(e_self);
    dsum += wself;
    float inv = 1.f / dsum;
    if (half == 0) {
        unsigned sv = hb[(size_t)node * 32 + sl];
        float* op = out + (size_t)node * 64;
        int c0 = 2 * sl;
        float o0 = bias[c0] + (acc0 + wself * b2f_lo(sv)) * inv;
        float o1 = bias[c0 + 1] + (acc1 + wself * b2f_hi(sv)) * inv;
        *(float2*)(op + c0) = make_float2(o0, o1);
    }
}

// ---------------- segmented mean pool: one block per graph ----------------
__global__ void pool_seg_kernel(const float* __restrict__ x, const int* __restrict__ brow,
                                float* __restrict__ pooled) {
    __shared__ float red[4][64];
    int g = blockIdx.x;
    int lane = threadIdx.x & 63, w = threadIdx.x >> 6;
    int beg = brow[g], end = brow[g + 1];
    float acc = 0.f;
    for (int n = beg + w; n < end; n += 4)
        acc += x[(size_t)n * 64 + lane];
    red[w][lane] = acc;
    __syncthreads();
    if (w == 0) {
        float s = red[0][lane] + red[1][lane] + red[2][lane] + red[3][lane];
        float cnt = (float)(end - beg);
        pooled[(size_t)g * 64 + lane] = s / fmaxf(cnt, 1.f);
    }
}

// ---------------- final: sigmoid((xs+xt)@lin_w + lin_b) ----------------
__global__ void final_kernel(const float* __restrict__ ps, const float* __restrict__ pt,
                             const float* __restrict__ lw, const float* __restrict__ lb,
                             float* __restrict__ out) {
    int g = blockIdx.x;
    int c = threadIdx.x;
    if (c >= 27) return;
    float acc = lb[c];
    #pragma unroll 8
    for (int k = 0; k < 64; k++) {
        float xv = ps[g * 64 + k] + pt[g * 64 + k];
        acc += xv * lw[k * 27 + c];
    }
    out[g * 27 + c] = 1.f / (1.f + expf(-acc));
}

static void build_csr(const int* src, const int* dst, int* rowptr, int* deg, int* bsum, int* col,
                      hipStream_t stream) {
    int edge_blocks = (EE + 255) / 256;
    int G = (NN + 1023) / 1024;
    hipMemsetAsync(deg, 0, NN * sizeof(int), stream);
    hist_kernel<<<edge_blocks, 256, 0, stream>>>(dst, deg, EE);
    scan_sum_kernel<<<G, 256, 0, stream>>>(deg, bsum, NN);
    scan_top_kernel<<<1, 256, 0, stream>>>(bsum, G);
    scan_write_kernel<<<G, 256, 0, stream>>>(deg, bsum, rowptr, NN, EE);
    hipMemsetAsync(deg, 0, NN * sizeof(int), stream);
    fill_kernel<<<edge_blocks, 256, 0, stream>>>(src, dst, rowptr, deg, col, EE);
}

// ---------------- one branch: conv1(128) -> conv2(64) -> pool ----------------
static void run_branch(const float* x,
                       const float* W1, const float* as1, const float* ad1, const float* b1,
                       const float* W2, const float* as2, const float* ad2, const float* b2,
                       const int* rowptr, const int* col, const int* batch,
                       unsigned* hb, unsigned* out1b, float* out2,
                       float* al_s, float* al_d, unsigned short* WT,
                       int* brow, float* pooled, hipStream_t stream) {
    int gemm_blocks = (NN + 127) / 128;
    int gather_blocks = (NN + 3) / 4;

    wt_kernel<<<(256 * 128 + 255) / 256, 256, 0, stream>>>(W1, WT, 256, 128);
    gemm_fused_kernel<256, 128, false><<<gemm_blocks, 256, 0, stream>>>(
        x, WT, as1, ad1, hb, al_s, al_d, NN);
    gat_gather128_kernel<<<gather_blocks, 256, 0, stream>>>(
        rowptr, col, al_s, al_d, hb, b1, out1b, NN);

    wt_kernel<<<(128 * 64 + 255) / 256, 256, 0, stream>>>(W2, WT, 128, 64);
    gemm_fused_kernel<128, 64, true><<<gemm_blocks, 256, 0, stream>>>(
        out1b, WT, as2, ad2, hb, al_s, al_d, NN);
    gat_gather64_kernel<<<gather_blocks, 256, 0, stream>>>(
        rowptr, col, al_s, al_d, hb, b2, out2, NN);

    brow_kernel<<<(BB + 1 + 255) / 256, 256, 0, stream>>>(batch, brow, NN, BB);
    pool_seg_kernel<<<BB, 256, 0, stream>>>(out2, brow, pooled);
}

extern "C" void kernel_launch(void* const* d_in, const int* in_sizes, int n_in,
                              void* d_out, int out_size, void* d_ws, size_t ws_size,
                              hipStream_t stream) {
    const float* x_s = (const float*)d_in[0];
    const float* x_t = (const float*)d_in[1];
    const int* ei_s = (const int*)d_in[2];
    const int* ei_t = (const int*)d_in[3];
    const int* xs_batch = (const int*)d_in[4];
    const int* xt_batch = (const int*)d_in[5];
    const float* W_s1 = (const float*)d_in[6];
    const float* a_src_s1 = (const float*)d_in[7];
    const float* a_dst_s1 = (const float*)d_in[8];
    const float* b_s1 = (const float*)d_in[9];
    const float* W_s2 = (const float*)d_in[10];
    const float* a_src_s2 = (const float*)d_in[11];
    const float* a_dst_s2 = (const float*)d_in[12];
    const float* b_s2 = (const float*)d_in[13];
    const float* W_t1 = (const float*)d_in[14];
    const float* a_src_t1 = (const float*)d_in[15];
    const float* a_dst_t1 = (const float*)d_in[16];
    const float* b_t1 = (const float*)d_in[17];
    const float* W_t2 = (const float*)d_in[18];
    const float* a_src_t2 = (const float*)d_in[19];
    const float* a_dst_t2 = (const float*)d_in[20];
    const float* b_t2 = (const float*)d_in[21];
    const float* lin_w = (const float*)d_in[22];
    const float* lin_b = (const float*)d_in[23];
    float* out = (float*)d_out;

    // workspace carve-up (4B units)
    unsigned* hb = (unsigned*)d_ws;                     // NN*64 dwords (bf16 h, both layers)
    unsigned* out1b = hb + (size_t)NN * 64;             // NN*64 dwords (bf16 conv1 out)
    float* out2 = (float*)(out1b + (size_t)NN * 64);    // NN*64 f32 (conv2 out)
    float* al_s = out2 + (size_t)NN * 64;               // NN
    float* al_d = al_s + NN;                            // NN
    float* pooled_s = al_d + NN;                        // BB*64
    float* pooled_t = pooled_s + (size_t)BB * 64;       // BB*64
    int* col = (int*)(pooled_t + (size_t)BB * 64);      // EE
    unsigned short* WT = (unsigned short*)(col + EE);   // 32768 bf16
    int* rowptr = (int*)(WT + 32768);                   // NN+1
    int* deg = rowptr + NN + 1;                         // NN
    int* brow = deg + NN;                               // BB+1
    int* bsum = brow + BB + 1;                          // 128

    const int* src_s = ei_s;
    const int* dst_s = ei_s + EE;
    const int* src_t = ei_t;
    const int* dst_t = ei_t + EE;

    // ----- branch s -----
    build_csr(src_s, dst_s, rowptr, deg, bsum, col, stream);
    run_branch(x_s, W_s1, a_src_s1, a_dst_s1, b_s1, W_s2, a_src_s2, a_dst_s2, b_s2,
               rowptr, col, xs_batch, hb, out1b, out2, al_s, al_d, WT, brow, pooled_s, stream);

    // ----- branch t -----
    build_csr(src_t, dst_t, rowptr, deg, bsum, col, stream);
    run_branch(x_t, W_t1, a_src_t1, a_dst_t1, b_t1, W_t2, a_src_t2, a_dst_t2, b_t2,
               rowptr, col, xt_batch, hb, out1b, out2, al_s, al_d, WT, brow, pooled_t, stream);

    // ----- head -----
    final_kernel<<<BB, 32, 0, stream>>>(pooled_s, pooled_t, lin_w, lin_b, out);
}